// Round 9
// baseline (2356.863 us; speedup 1.0000x reference)
//
#include <hip/hip_runtime.h>

// Problem constants
#define BATCH   4
#define SEQ     8192
#define NTOK    32768      // BATCH*SEQ
#define FF      32
#define FDIM    128
#define DD      512
#define HEADS   8
#define HDIM    64
#define WINSZ   256
#define NBLK    32         // SEQ/WINSZ
#define LAYERS  4

typedef unsigned short u16;
typedef __attribute__((ext_vector_type(8))) short bf16x8;
typedef __attribute__((ext_vector_type(4))) float f32x4;

__device__ __forceinline__ float u2f(u16 u) {
  return __uint_as_float(((unsigned int)u) << 16);
}
// round-half-up bf16 (2 VALU ops)
__device__ __forceinline__ u16 f2u(float f) {
  return (u16)((__float_as_uint(f) + 0x8000u) >> 16);
}
__device__ __forceinline__ unsigned int pk2(float a, float b) {
  return ((__float_as_uint(a) + 0x8000u) >> 16) |
         ((__float_as_uint(b) + 0x8000u) & 0xffff0000u);
}
__device__ __forceinline__ void ld8(const u16* __restrict__ p, float* o) {
  ushort4 q0 = *(const ushort4*)p;
  ushort4 q1 = *(const ushort4*)(p + 4);
  o[0]=u2f(q0.x); o[1]=u2f(q0.y); o[2]=u2f(q0.z); o[3]=u2f(q0.w);
  o[4]=u2f(q1.x); o[5]=u2f(q1.y); o[6]=u2f(q1.z); o[7]=u2f(q1.w);
}
__device__ __forceinline__ void st8(u16* __restrict__ p, const float* v) {
  uint4 o;
  o.x = pk2(v[0], v[1]); o.y = pk2(v[2], v[3]);
  o.z = pk2(v[4], v[5]); o.w = pk2(v[6], v[7]);
  *(uint4*)p = o;
}
// async global->LDS, 16B per lane; LDS dest = wave-uniform base + lane*16
__device__ __forceinline__ void gl_lds16(const u16* g, u16* l) {
  __builtin_amdgcn_global_load_lds(
      (const __attribute__((address_space(1))) void*)g,
      (__attribute__((address_space(3))) void*)l, 16, 0, 0);
}

// ---------------------------------------------------------------------------
// Embedding: fe = x@W_feat + b_feat ; cat = [fe, emb_temp[ts]]
// ---------------------------------------------------------------------------
__global__ __launch_bounds__(128) void embed_kernel(
    const float* __restrict__ x, const int* __restrict__ ts,
    const float* __restrict__ W_feat, const float* __restrict__ b_feat,
    const float* __restrict__ emb, u16* __restrict__ cat)
{
  const int t = blockIdx.x;
  const int j = threadIdx.x;   // 0..127
  __shared__ float xs[FF];
  if (j < FF) xs[j] = x[(size_t)t*FF + j];
  __syncthreads();
  float fe = b_feat[j];
  #pragma unroll
  for (int f = 0; f < FF; ++f) fe += xs[f] * W_feat[f*FDIM + j];
  cat[(size_t)t*256 + j] = f2u(fe);
  const int tv = ts[t];
  cat[(size_t)t*256 + 128 + j] = f2u(emb[(size_t)tv*FDIM + j]);
}

// ---------------------------------------------------------------------------
// Weight transpose+convert: src fp32 [K][512] -> dst bf16 [512][K]
// ---------------------------------------------------------------------------
__global__ __launch_bounds__(256) void transpose_w(
    const float* __restrict__ src, u16* __restrict__ dst, int K)
{
  __shared__ u16 t[32][34];
  const int bk = blockIdx.x*32, bn = blockIdx.y*32;
  const int c = threadIdx.x & 31, r8 = threadIdx.x >> 5;
  #pragma unroll
  for (int rr = 0; rr < 32; rr += 8)
    t[rr + r8][c] = f2u(src[(size_t)(bk + rr + r8)*512 + bn + c]);
  __syncthreads();
  #pragma unroll
  for (int rr = 0; rr < 32; rr += 8)
    dst[(size_t)(bn + rr + r8)*K + bk + c] = t[c][rr + r8];
}

// Weight slot offsets (u16 elements) within the per-layer buffer
#define WQO 0
#define WKO 262144
#define WVO 524288
#define WOO 786432
#define WGO 1048576
#define WUO 1572864

__global__ __launch_bounds__(256) void convert_layer(
    const float* __restrict__ Wq, const float* __restrict__ Wk,
    const float* __restrict__ Wv, const float* __restrict__ Wo,
    const float* __restrict__ Wg, const float* __restrict__ Wu,
    u16* __restrict__ out)
{
  __shared__ u16 t[32][34];
  const int z = blockIdx.z;
  const int K = (z < 4) ? 512 : 1024;
  const int bk = blockIdx.x*32;
  if (bk >= K) return;
  const int bn = blockIdx.y*32;
  const float* src = (z==0)?Wq:(z==1)?Wk:(z==2)?Wv:(z==3)?Wo:(z==4)?Wg:Wu;
  u16* dst = out + ((z<4) ? (size_t)z*262144 : (size_t)1048576 + (size_t)(z-4)*524288);
  const int c = threadIdx.x & 31, r8 = threadIdx.x >> 5;
  #pragma unroll
  for (int rr = 0; rr < 32; rr += 8)
    t[rr + r8][c] = f2u(src[(size_t)(bk + rr + r8)*512 + bn + c]);
  __syncthreads();
  #pragma unroll
  for (int rr = 0; rr < 32; rr += 8)
    dst[(size_t)(bn + rr + r8)*K + bk + c] = t[c][rr + r8];
}

// conv_w fp32 [o,ch,j] -> bf16 [o][k=j*512+ch]  (transposed-B GEMM-ready)
__global__ __launch_bounds__(256) void repack_conv(
    const float* __restrict__ cw, u16* __restrict__ dst)
{
  const int t = blockIdx.x*256 + threadIdx.x;     // < 512*2048
  const int o  = t >> 11;
  const int kk = t & 2047;
  const int j  = kk >> 9;
  const int ch = kk & 511;
  dst[t] = f2u(cw[(size_t)o*2048 + ch*4 + j]);
}

// ---------------------------------------------------------------------------
// MFMA GEMM (m97 structure), fused-output variants.
// MODE 0: C0 = A@B + b0                       (rowmajor [M][512])
// MODE 1: qkv fused N=1536: seg0->C0(q), seg1->C1(k) rowmajor; seg2->C2(v^T)
// MODE 2: gate/upd fused N=1024: seg0->sigmoid->C0, seg1->C1 (rowmajor)
// A bf16 dual-source (concat), Bt bf16 [N][K], fp32 accum, BK=32, 4 waves.
// ---------------------------------------------------------------------------
template<int MODE>
__global__ __launch_bounds__(256) void mfma_gemm(
    const u16* __restrict__ A1, const u16* __restrict__ A2, int K1, int K,
    const u16* __restrict__ Bt,
    const float* __restrict__ b0, const float* __restrict__ b1,
    const float* __restrict__ b2,
    u16* __restrict__ C0, u16* __restrict__ C1, u16* __restrict__ C2)
{
  __shared__ u16 Al[128*32];
  __shared__ u16 Bl[128*32];
  const int tid  = threadIdx.x;
  const int lane = tid & 63;
  const int wave = tid >> 6;
  const int wm = (wave & 1) * 64;
  const int wn = (wave >> 1) * 64;
  const int m0 = blockIdx.y * 128;
  const int n0 = blockIdx.x * 128;
  const int cl = lane & 15, quad = lane >> 4;
  const int srow = wave*16 + (lane >> 2);
  const int sk   = (lane & 3) * 8;
  u16* Adst = Al + wave*512;
  u16* Bdst = Bl + wave*512;
  const int K2 = K - K1;

  f32x4 acc[4][4];
  #pragma unroll
  for (int i = 0; i < 4; ++i)
    #pragma unroll
    for (int j = 0; j < 4; ++j)
      acc[i][j] = (f32x4){0.f, 0.f, 0.f, 0.f};

  for (int k0 = 0; k0 < K; k0 += 32) {
    const int kc = k0 + sk;
    const u16* a0 = (kc < K1) ? A1 + (size_t)(m0 + srow)*K1 + kc
                              : A2 + (size_t)(m0 + srow)*K2 + (kc - K1);
    const u16* a1 = (kc < K1) ? A1 + (size_t)(m0 + srow + 64)*K1 + kc
                              : A2 + (size_t)(m0 + srow + 64)*K2 + (kc - K1);
    gl_lds16(a0, Adst);
    gl_lds16(a1, Adst + 2048);
    gl_lds16(Bt + (size_t)(n0 + srow)*K + kc,      Bdst);
    gl_lds16(Bt + (size_t)(n0 + srow + 64)*K + kc, Bdst + 2048);
    __syncthreads();
    bf16x8 af[4], bfr[4];
    #pragma unroll
    for (int i = 0; i < 4; ++i) {
      af[i]  = *(const bf16x8*)(Al + (wm + i*16 + cl)*32 + quad*8);
      bfr[i] = *(const bf16x8*)(Bl + (wn + i*16 + cl)*32 + quad*8);
    }
    #pragma unroll
    for (int i = 0; i < 4; ++i)
      #pragma unroll
      for (int j = 0; j < 4; ++j)
        acc[i][j] = __builtin_amdgcn_mfma_f32_16x16x32_bf16(
            af[i], bfr[j], acc[i][j], 0, 0, 0);
    __syncthreads();
  }
  const int rq = quad * 4;
  const int colbase = n0 + wn;          // 64-aligned -> seg uniform per wave
  const int seg = colbase >> 9;
  const float* bias = (MODE == 0) ? b0 : (seg == 0 ? b0 : (seg == 1 ? b1 : b2));
  u16* dstR = (seg == 0) ? C0 : C1;     // rowmajor dest (seg<2)
  #pragma unroll
  for (int j = 0; j < 4; ++j) {
    const int lc = (colbase & 511) + j*16 + cl;
    const float bb = bias[lc];
    #pragma unroll
    for (int i = 0; i < 4; ++i) {
      const int rbase = m0 + wm + i*16 + rq;
      float v[4];
      #pragma unroll
      for (int r = 0; r < 4; ++r) {
        float t = acc[i][j][r] + bb;
        if (MODE == 2 && seg == 0) t = 1.0f / (1.0f + __expf(-t));
        v[r] = t;
      }
      if (MODE == 1 && seg == 2) {
        uint2 o2;
        o2.x = pk2(v[0], v[1]); o2.y = pk2(v[2], v[3]);
        *(uint2*)(C2 + (size_t)lc*NTOK + rbase) = o2;
      } else {
        #pragma unroll
        for (int r = 0; r < 4; ++r)
          dstR[(size_t)(rbase + r)*DD + lc] = f2u(v[r]);
      }
    }
  }
}

// ---------------------------------------------------------------------------
// MFMA flash attention v4: S^T formulation, no-max softmax, shuffle-based P
// (no LDS P buffer -> 35.8 KB LDS, launch_bounds(256,3) -> 12 waves/CU).
// Block = (b, window n, head); 4 waves x 64 queries.
// Keys [(n-1)*W,(n+1)*W); n==0 -> only [0,W).
// P B-operand fragments built in-register from S^T C-layout via __shfl:
//   dest (cl,quad,j): i=2kh+(quad>>1), quad'=2(quad&1)+(j>>2), r=j&3,
//   src lane = cl + 16*quad'.
// vt input dim-major [512][NTOK] (written transposed by the V-GEMM epilogue).
// ---------------------------------------------------------------------------
#define EXPSC 0.18033688f   // 0.125 * log2(e)
__global__ __launch_bounds__(256, 3) void attn_kernel(
    const u16* __restrict__ q, const u16* __restrict__ k,
    const u16* __restrict__ vt, u16* __restrict__ ctx)
{
  __shared__ u16 Ks[128*72];
  __shared__ u16 Vl[64*136];
  const int bid  = blockIdx.x;
  const int head = bid & 7;
  const int n    = (bid >> 3) & 31;
  const int b    = bid >> 8;
  const int tid  = threadIdx.x;
  const int lane = tid & 63;
  const int wave = tid >> 6;
  const int cl   = lane & 15;
  const int quad = lane >> 4;
  const int qtok0 = b*SEQ + n*WINSZ + wave*64;
  const bool hi2 = (lane >= 32);              // quad>=2 -> use sacc[2kh+1]
  const int srcA = cl + ((quad & 1) << 5);    // lane of quad' = 2(quad&1)
  const int srcB = srcA + 16;                 // lane of quad' = 2(quad&1)+1

  // Q fragments (B-operand: n=q rows, k-contiguous)
  bf16x8 qf[4][2];
  #pragma unroll
  for (int jf = 0; jf < 4; ++jf)
    #pragma unroll
    for (int kh = 0; kh < 2; ++kh)
      qf[jf][kh] = *(const bf16x8*)(q + (size_t)(qtok0 + jf*16 + cl)*DD
                                      + head*HDIM + kh*32 + quad*8);

  f32x4 oacc[4][4];   // [jd][jq]
  #pragma unroll
  for (int i = 0; i < 4; ++i)
    #pragma unroll
    for (int j = 0; j < 4; ++j)
      oacc[i][j] = (f32x4){0.f, 0.f, 0.f, 0.f};
  float lrun[4] = {0.f, 0.f, 0.f, 0.f};

  const int r0 = (n == 0) ? WINSZ : 0;
  const int base_tok = b*SEQ + (n - 1)*WINSZ;
  const int ksr = tid >> 1;          // K stage: key row 0..127
  const int ksc = (tid & 1) * 32;    // 64 B per thread
  const int vsr = tid >> 2;          // V stage: dim row 0..63
  const int vsc = (tid & 3) * 32;    // 64 B per thread

  for (int c0 = r0; c0 < 2*WINSZ; c0 += 128) {
    // ---- stage K [128 keys][64 d] and V^T [64 d][128 keys], 64 B/thread ----
    {
      const u16* ksrc = k + (size_t)(base_tok + c0 + ksr)*DD + head*HDIM + ksc;
      uint4* kd = (uint4*)(Ks + ksr*72 + ksc);
      kd[0] = ((const uint4*)ksrc)[0];
      kd[1] = ((const uint4*)ksrc)[1];
      kd[2] = ((const uint4*)ksrc)[2];
      kd[3] = ((const uint4*)ksrc)[3];
      const u16* vsrc = vt + (size_t)(head*HDIM + vsr)*NTOK + base_tok + c0 + vsc;
      uint4* vd = (uint4*)(Vl + vsr*136 + vsc);
      vd[0] = ((const uint4*)vsrc)[0];
      vd[1] = ((const uint4*)vsrc)[1];
      vd[2] = ((const uint4*)vsrc)[2];
      vd[3] = ((const uint4*)vsrc)[3];
    }
    __syncthreads();
    #pragma unroll
    for (int half = 0; half < 2; ++half) {
      #pragma unroll
      for (int jf = 0; jf < 4; ++jf) {
        // ---- S^T = K·Q^T for this jf: sa[i] = D[key 16i+4quad+r][q 16jf+cl]
        f32x4 sa[4];
        #pragma unroll
        for (int i = 0; i < 4; ++i) {
          const u16* kr = Ks + (half*64 + i*16 + cl)*72 + quad*8;
          bf16x8 k0 = *(const bf16x8*)kr;
          bf16x8 k1 = *(const bf16x8*)(kr + 32);
          f32x4 s = (f32x4){0.f, 0.f, 0.f, 0.f};
          s = __builtin_amdgcn_mfma_f32_16x16x32_bf16(k0, qf[jf][0], s, 0, 0, 0);
          s = __builtin_amdgcn_mfma_f32_16x16x32_bf16(k1, qf[jf][1], s, 0, 0, 0);
          sa[i] = s;
        }
        // ---- softmax numerators (no max), pack to bf16 pairs ----
        float rs = 0.f;
        unsigned int pd[4][2];
        #pragma unroll
        for (int i = 0; i < 4; ++i) {
          const float p0 = exp2f(sa[i][0] * EXPSC);
          const float p1 = exp2f(sa[i][1] * EXPSC);
          const float p2 = exp2f(sa[i][2] * EXPSC);
          const float p3 = exp2f(sa[i][3] * EXPSC);
          rs += (p0 + p1) + (p2 + p3);
          pd[i][0] = pk2(p0, p1);
          pd[i][1] = pk2(p2, p3);
        }
        rs += __shfl_xor(rs, 16, 64);
        rs += __shfl_xor(rs, 32, 64);
        lrun[jf] += rs;
        // ---- build P B-frags via shuffles, PV MFMA ----
        #pragma unroll
        for (int kh = 0; kh < 2; ++kh) {
          const int aA0 = __shfl((int)pd[2*kh][0],   srcA, 64);
          const int aB0 = __shfl((int)pd[2*kh+1][0], srcA, 64);
          const int aA1 = __shfl((int)pd[2*kh][1],   srcA, 64);
          const int aB1 = __shfl((int)pd[2*kh+1][1], srcA, 64);
          const int cA0 = __shfl((int)pd[2*kh][0],   srcB, 64);
          const int cB0 = __shfl((int)pd[2*kh+1][0], srcB, 64);
          const int cA1 = __shfl((int)pd[2*kh][1],   srcB, 64);
          const int cB1 = __shfl((int)pd[2*kh+1][1], srcB, 64);
          uint4 pw;
          pw.x = hi2 ? aB0 : aA0;
          pw.y = hi2 ? aB1 : aA1;
          pw.z = hi2 ? cB0 : cA0;
          pw.w = hi2 ? cB1 : cA1;
          bf16x8 pf = *(bf16x8*)&pw;
          #pragma unroll
          for (int jd = 0; jd < 4; ++jd) {
            bf16x8 vf = *(const bf16x8*)(Vl + (jd*16 + cl)*136
                                            + half*64 + kh*32 + quad*8);
            oacc[jd][jf] = __builtin_amdgcn_mfma_f32_16x16x32_bf16(
                vf, pf, oacc[jd][jf], 0, 0, 0);
          }
        }
      }
    }
    __syncthreads();
  }
  // ---- epilogue: per lane q = jq*16+cl, dims jd*16+quad*4+r (8B stores) ----
  #pragma unroll
  for (int jq = 0; jq < 4; ++jq) {
    const float inv = 1.0f / lrun[jq];
    u16* crow = ctx + (size_t)(qtok0 + jq*16 + cl)*DD + head*HDIM + quad*4;
    #pragma unroll
    for (int jd = 0; jd < 4; ++jd) {
      uint2 o2;
      o2.x = pk2(oacc[jd][jq][0]*inv, oacc[jd][jq][1]*inv);
      o2.y = pk2(oacc[jd][jq][2]*inv, oacc[jd][jq][3]*inv);
      *(uint2*)(crow + jd*16) = o2;
    }
  }
}

// ---------------------------------------------------------------------------
// new_mem = g*u + (1-g)*mem ; h = LN(a + new_mem)  (wave per token)
// ---------------------------------------------------------------------------
__global__ __launch_bounds__(256) void memln_kernel(
    const u16* __restrict__ a, const u16* __restrict__ gate, const u16* __restrict__ upd,
    u16* __restrict__ mem, const float* __restrict__ lg, const float* __restrict__ lb,
    u16* __restrict__ h)
{
  const int lane = threadIdx.x & 63;
  const int wave = threadIdx.x >> 6;
  const int t = blockIdx.x*4 + wave;
  const size_t base = (size_t)t*DD + lane*8;
  float av[8], gv[8], uv[8], mv[8];
  ld8(a + base, av); ld8(gate + base, gv); ld8(upd + base, uv); ld8(mem + base, mv);
  float s[8], nm[8], sum = 0.f, sq = 0.f;
  #pragma unroll
  for (int e = 0; e < 8; ++e) {
    nm[e] = gv[e]*uv[e] + (1.0f - gv[e])*mv[e];
    s[e]  = av[e] + nm[e];
    sum  += s[e]; sq += s[e]*s[e];
  }
  st8(mem + base, nm);
  for (int o = 32; o > 0; o >>= 1) {
    sum += __shfl_xor(sum, o, 64);
    sq  += __shfl_xor(sq,  o, 64);
  }
  const float mean = sum * (1.0f/512.0f);
  const float var  = sq  * (1.0f/512.0f) - mean*mean;
  const float r = rsqrtf(var + 1e-5f);
  float y[8];
  #pragma unroll
  for (int e = 0; e < 8; ++e) {
    const int ch = lane*8 + e;
    y[e] = (s[e] - mean)*r*lg[ch] + lb[ch];
  }
  st8(h + base, y);
}

// ---------------------------------------------------------------------------
// final: o = LN(LN(c, cn), on) ; out = o @ W_out + b_out  (fp32 out)
// ---------------------------------------------------------------------------
__global__ __launch_bounds__(256) void final_kernel(
    const u16* __restrict__ c,
    const float* __restrict__ cng, const float* __restrict__ cnb,
    const float* __restrict__ ong, const float* __restrict__ onb,
    const float* __restrict__ Wout, const float* __restrict__ bout,
    float* __restrict__ out)
{
  __shared__ float ybuf[4][512];
  const int lane = threadIdx.x & 63;
  const int wave = threadIdx.x >> 6;
  const int t = blockIdx.x*4 + wave;
  const size_t base = (size_t)t*DD + lane*8;
  float x[8];
  ld8(c + base, x);
  float sum = 0.f, sq = 0.f;
  #pragma unroll
  for (int e = 0; e < 8; ++e) { sum += x[e]; sq += x[e]*x[e]; }
  for (int o = 32; o > 0; o >>= 1) { sum += __shfl_xor(sum, o, 64); sq += __shfl_xor(sq, o, 64); }
  float mean = sum * (1.0f/512.0f);
  float var  = sq  * (1.0f/512.0f) - mean*mean;
  float r = rsqrtf(var + 1e-5f);
  float y[8];
  float sum2 = 0.f, sq2 = 0.f;
  #pragma unroll
  for (int e = 0; e < 8; ++e) {
    const int ch = lane*8 + e;
    y[e] = (x[e] - mean)*r*cng[ch] + cnb[ch];
    sum2 += y[e]; sq2 += y[e]*y[e];
  }
  for (int o = 32; o > 0; o >>= 1) { sum2 += __shfl_xor(sum2, o, 64); sq2 += __shfl_xor(sq2, o, 64); }
  mean = sum2 * (1.0f/512.0f);
  var  = sq2  * (1.0f/512.0f) - mean*mean;
  r = rsqrtf(var + 1e-5f);
  #pragma unroll
  for (int e = 0; e < 8; ++e) {
    const int ch = lane*8 + e;
    ybuf[wave][ch] = (y[e] - mean)*r*ong[ch] + onb[ch];
  }
  __syncthreads();
  if (lane < FF) {
    float acc = bout[lane];
    for (int ch = 0; ch < 512; ++ch)
      acc += ybuf[wave][ch] * Wout[ch*FF + lane];
    out[(size_t)t*FF + lane] = acc;
  }
}

// ---------------------------------------------------------------------------
// Workspace (164 MB):
//   mem @0 (32MB persistent bf16), B1 @32MB, B2 @64MB, B3 @96MB, B4 @128MB,
//   WB @160MB (4MB: per-layer transposed bf16 weights / W_emb^T / conv W^T)
// ---------------------------------------------------------------------------
extern "C" void kernel_launch(void* const* d_in, const int* in_sizes, int n_in,
                              void* d_out, int out_size, void* d_ws, size_t ws_size,
                              hipStream_t stream)
{
  const float* x      = (const float*)d_in[0];
  const int*   tstamp = (const int*)d_in[1];
  const float* W_feat = (const float*)d_in[2];
  const float* b_feat = (const float*)d_in[3];
  const float* emb_t  = (const float*)d_in[4];
  const float* W_emb  = (const float*)d_in[5];
  const float* b_emb  = (const float*)d_in[6];
  const float* Wq = (const float*)d_in[7];   const float* bq = (const float*)d_in[8];
  const float* Wk = (const float*)d_in[9];   const float* bk = (const float*)d_in[10];
  const float* Wv = (const float*)d_in[11];  const float* bv = (const float*)d_in[12];
  const float* Wo = (const float*)d_in[13];  const float* bo = (const float*)d_in[14];
  const float* Wg = (const float*)d_in[15];  const float* bg = (const float*)d_in[16];
  const float* Wu = (const float*)d_in[17];  const float* bu = (const float*)d_in[18];
  const float* lng = (const float*)d_in[19]; const float* lnb = (const float*)d_in[20];
  const float* convw = (const float*)d_in[21]; const float* convb = (const float*)d_in[22];
  const float* cng = (const float*)d_in[23]; const float* cnb = (const float*)d_in[24];
  const float* ong = (const float*)d_in[25]; const float* onb = (const float*)d_in[26];
  const float* Wout = (const float*)d_in[27]; const float* bout = (const float*)d_in[28];
  float* outp = (float*)d_out;

  char* ws = (char*)d_ws;
  const size_t MB = 1024u*1024u;
  u16* mem = (u16*)ws;
  u16* B1  = (u16*)(ws + 32*MB);
  u16* B2  = (u16*)(ws + 64*MB);
  u16* B3  = (u16*)(ws + 96*MB);
  u16* B4  = (u16*)(ws + 128*MB);
  u16* WB  = (u16*)(ws + 160*MB);

  hipMemsetAsync(mem, 0, (size_t)NTOK*DD*sizeof(u16), stream);

  // Embedding: cat -> B2 ; W_emb^T -> WB ; h -> B1
  embed_kernel<<<NTOK, 128, 0, stream>>>(x, tstamp, W_feat, b_feat, emb_t, B2);
  transpose_w<<<dim3(8, 16), 256, 0, stream>>>(W_emb, WB, 256);
  mfma_gemm<0><<<dim3(4, NTOK/128), 256, 0, stream>>>(
      B2, B2, 256, 256, WB, b_emb, nullptr, nullptr, B1, nullptr, nullptr);

  for (int l = 0; l < LAYERS; ++l) {
    convert_layer<<<dim3(32, 16, 6), 256, 0, stream>>>(
        Wq + (size_t)l*DD*DD, Wk + (size_t)l*DD*DD, Wv + (size_t)l*DD*DD,
        Wo + (size_t)l*DD*DD, Wg + (size_t)l*2*DD*DD, Wu + (size_t)l*2*DD*DD, WB);
    // fused qkv: q -> B2, k -> B3, v^T -> B4
    mfma_gemm<1><<<dim3(12, NTOK/128), 256, 0, stream>>>(
        B1, B1, 512, 512, WB + WQO,
        bq + l*DD, bk + l*DD, bv + l*DD, B2, B3, B4);
    // ctx -> B1 (h dead)
    attn_kernel<<<BATCH*NBLK*HEADS, 256, 0, stream>>>(B2, B3, B4, B1);
    // a = ctx @ Wo + bo -> B2
    mfma_gemm<0><<<dim3(4, NTOK/128), 256, 0, stream>>>(
        B1, B1, 512, 512, WB + WOO, bo + l*DD, nullptr, nullptr,
        B2, nullptr, nullptr);
    // fused gate/upd: gate -> B3 (sigmoid), upd -> B4
    mfma_gemm<2><<<dim3(8, NTOK/128), 256, 0, stream>>>(
        B2, mem, 512, 1024, WB + WGO,
        bg + l*DD, bu + l*DD, nullptr, B3, B4, nullptr);
    // mem update + LN -> h (B1)
    memln_kernel<<<NTOK/4, 256, 0, stream>>>(
        B2, B3, B4, mem, lng + l*DD, lnb + l*DD, B1);
  }

  // Temporal conv as GEMM: A = h [8192, 2048]; conv W^T -> WB; c -> B3
  repack_conv<<<4096, 256, 0, stream>>>(convw, WB);
  mfma_gemm<0><<<dim3(4, 8192/128), 256, 0, stream>>>(
      B1, B1, 2048, 2048, WB, convb, nullptr, nullptr, B3, nullptr, nullptr);

  // LN -> LN -> out projection (fp32 out)
  final_kernel<<<8192/4, 256, 0, stream>>>(
      B3, cng, cnb, ong, onb, Wout, bout, outp);
}

// Round 10
// 1775.407 us; speedup vs baseline: 1.3275x; 1.3275x over previous
//
#include <hip/hip_runtime.h>

// Problem constants
#define BATCH   4
#define SEQ     8192
#define NTOK    32768      // BATCH*SEQ
#define FF      32
#define FDIM    128
#define DD      512
#define HEADS   8
#define HDIM    64
#define WINSZ   256
#define NBLK    32         // SEQ/WINSZ
#define LAYERS  4

typedef unsigned short u16;
typedef __attribute__((ext_vector_type(8))) short bf16x8;
typedef __attribute__((ext_vector_type(4))) float f32x4;

__device__ __forceinline__ float u2f(u16 u) {
  return __uint_as_float(((unsigned int)u) << 16);
}
// round-half-up bf16 (2 VALU ops)
__device__ __forceinline__ u16 f2u(float f) {
  return (u16)((__float_as_uint(f) + 0x8000u) >> 16);
}
__device__ __forceinline__ unsigned int pk2(float a, float b) {
  return ((__float_as_uint(a) + 0x8000u) >> 16) |
         ((__float_as_uint(b) + 0x8000u) & 0xffff0000u);
}
__device__ __forceinline__ void ld8(const u16* __restrict__ p, float* o) {
  ushort4 q0 = *(const ushort4*)p;
  ushort4 q1 = *(const ushort4*)(p + 4);
  o[0]=u2f(q0.x); o[1]=u2f(q0.y); o[2]=u2f(q0.z); o[3]=u2f(q0.w);
  o[4]=u2f(q1.x); o[5]=u2f(q1.y); o[6]=u2f(q1.z); o[7]=u2f(q1.w);
}
__device__ __forceinline__ void st8(u16* __restrict__ p, const float* v) {
  uint4 o;
  o.x = pk2(v[0], v[1]); o.y = pk2(v[2], v[3]);
  o.z = pk2(v[4], v[5]); o.w = pk2(v[6], v[7]);
  *(uint4*)p = o;
}
// async global->LDS, 16B per lane; LDS dest = wave-uniform base + lane*16
__device__ __forceinline__ void gl_lds16(const u16* g, u16* l) {
  __builtin_amdgcn_global_load_lds(
      (const __attribute__((address_space(1))) void*)g,
      (__attribute__((address_space(3))) void*)l, 16, 0, 0);
}

// ---------------------------------------------------------------------------
// Embedding: fe = x@W_feat + b_feat ; cat = [fe, emb_temp[ts]]
// ---------------------------------------------------------------------------
__global__ __launch_bounds__(128) void embed_kernel(
    const float* __restrict__ x, const int* __restrict__ ts,
    const float* __restrict__ W_feat, const float* __restrict__ b_feat,
    const float* __restrict__ emb, u16* __restrict__ cat)
{
  const int t = blockIdx.x;
  const int j = threadIdx.x;   // 0..127
  __shared__ float xs[FF];
  if (j < FF) xs[j] = x[(size_t)t*FF + j];
  __syncthreads();
  float fe = b_feat[j];
  #pragma unroll
  for (int f = 0; f < FF; ++f) fe += xs[f] * W_feat[f*FDIM + j];
  cat[(size_t)t*256 + j] = f2u(fe);
  const int tv = ts[t];
  cat[(size_t)t*256 + 128 + j] = f2u(emb[(size_t)tv*FDIM + j]);
}

// ---------------------------------------------------------------------------
// Weight transpose+convert: src fp32 [K][512] -> dst bf16 [512][K]
// ---------------------------------------------------------------------------
__global__ __launch_bounds__(256) void transpose_w(
    const float* __restrict__ src, u16* __restrict__ dst, int K)
{
  __shared__ u16 t[32][34];
  const int bk = blockIdx.x*32, bn = blockIdx.y*32;
  const int c = threadIdx.x & 31, r8 = threadIdx.x >> 5;
  #pragma unroll
  for (int rr = 0; rr < 32; rr += 8)
    t[rr + r8][c] = f2u(src[(size_t)(bk + rr + r8)*512 + bn + c]);
  __syncthreads();
  #pragma unroll
  for (int rr = 0; rr < 32; rr += 8)
    dst[(size_t)(bn + rr + r8)*K + bk + c] = t[c][rr + r8];
}

// Weight slot offsets (u16 elements) within the per-layer buffer
#define WQO 0
#define WKO 262144
#define WVO 524288
#define WOO 786432
#define WGO 1048576
#define WUO 1572864

__global__ __launch_bounds__(256) void convert_layer(
    const float* __restrict__ Wq, const float* __restrict__ Wk,
    const float* __restrict__ Wv, const float* __restrict__ Wo,
    const float* __restrict__ Wg, const float* __restrict__ Wu,
    u16* __restrict__ out)
{
  __shared__ u16 t[32][34];
  const int z = blockIdx.z;
  const int K = (z < 4) ? 512 : 1024;
  const int bk = blockIdx.x*32;
  if (bk >= K) return;
  const int bn = blockIdx.y*32;
  const float* src = (z==0)?Wq:(z==1)?Wk:(z==2)?Wv:(z==3)?Wo:(z==4)?Wg:Wu;
  u16* dst = out + ((z<4) ? (size_t)z*262144 : (size_t)1048576 + (size_t)(z-4)*524288);
  const int c = threadIdx.x & 31, r8 = threadIdx.x >> 5;
  #pragma unroll
  for (int rr = 0; rr < 32; rr += 8)
    t[rr + r8][c] = f2u(src[(size_t)(bk + rr + r8)*512 + bn + c]);
  __syncthreads();
  #pragma unroll
  for (int rr = 0; rr < 32; rr += 8)
    dst[(size_t)(bn + rr + r8)*K + bk + c] = t[c][rr + r8];
}

// conv_w fp32 [o,ch,j] -> bf16 [o][k=j*512+ch]  (transposed-B GEMM-ready)
__global__ __launch_bounds__(256) void repack_conv(
    const float* __restrict__ cw, u16* __restrict__ dst)
{
  const int t = blockIdx.x*256 + threadIdx.x;     // < 512*2048
  const int o  = t >> 11;
  const int kk = t & 2047;
  const int j  = kk >> 9;
  const int ch = kk & 511;
  dst[t] = f2u(cw[(size_t)o*2048 + ch*4 + j]);
}

// ---------------------------------------------------------------------------
// MFMA GEMM (m97 structure), fused-output variants.
// MODE 0: C0 = A@B + b0                       (rowmajor [M][512])
// MODE 1: qkv fused N=1536: seg0->C0(q), seg1->C1(k) rowmajor; seg2->C2(v^T)
// MODE 2: gate/upd fused N=1024: seg0->sigmoid->C0, seg1->C1 (rowmajor)
// A bf16 dual-source (concat), Bt bf16 [N][K], fp32 accum, BK=32, 4 waves.
// ---------------------------------------------------------------------------
template<int MODE>
__global__ __launch_bounds__(256) void mfma_gemm(
    const u16* __restrict__ A1, const u16* __restrict__ A2, int K1, int K,
    const u16* __restrict__ Bt,
    const float* __restrict__ b0, const float* __restrict__ b1,
    const float* __restrict__ b2,
    u16* __restrict__ C0, u16* __restrict__ C1, u16* __restrict__ C2)
{
  __shared__ u16 Al[128*32];
  __shared__ u16 Bl[128*32];
  const int tid  = threadIdx.x;
  const int lane = tid & 63;
  const int wave = tid >> 6;
  const int wm = (wave & 1) * 64;
  const int wn = (wave >> 1) * 64;
  const int m0 = blockIdx.y * 128;
  const int n0 = blockIdx.x * 128;
  const int cl = lane & 15, quad = lane >> 4;
  const int srow = wave*16 + (lane >> 2);
  const int sk   = (lane & 3) * 8;
  u16* Adst = Al + wave*512;
  u16* Bdst = Bl + wave*512;
  const int K2 = K - K1;

  f32x4 acc[4][4];
  #pragma unroll
  for (int i = 0; i < 4; ++i)
    #pragma unroll
    for (int j = 0; j < 4; ++j)
      acc[i][j] = (f32x4){0.f, 0.f, 0.f, 0.f};

  for (int k0 = 0; k0 < K; k0 += 32) {
    const int kc = k0 + sk;
    const u16* a0 = (kc < K1) ? A1 + (size_t)(m0 + srow)*K1 + kc
                              : A2 + (size_t)(m0 + srow)*K2 + (kc - K1);
    const u16* a1 = (kc < K1) ? A1 + (size_t)(m0 + srow + 64)*K1 + kc
                              : A2 + (size_t)(m0 + srow + 64)*K2 + (kc - K1);
    gl_lds16(a0, Adst);
    gl_lds16(a1, Adst + 2048);
    gl_lds16(Bt + (size_t)(n0 + srow)*K + kc,      Bdst);
    gl_lds16(Bt + (size_t)(n0 + srow + 64)*K + kc, Bdst + 2048);
    __syncthreads();
    bf16x8 af[4], bfr[4];
    #pragma unroll
    for (int i = 0; i < 4; ++i) {
      af[i]  = *(const bf16x8*)(Al + (wm + i*16 + cl)*32 + quad*8);
      bfr[i] = *(const bf16x8*)(Bl + (wn + i*16 + cl)*32 + quad*8);
    }
    #pragma unroll
    for (int i = 0; i < 4; ++i)
      #pragma unroll
      for (int j = 0; j < 4; ++j)
        acc[i][j] = __builtin_amdgcn_mfma_f32_16x16x32_bf16(
            af[i], bfr[j], acc[i][j], 0, 0, 0);
    __syncthreads();
  }
  const int rq = quad * 4;
  const int colbase = n0 + wn;          // 64-aligned -> seg uniform per wave
  const int seg = colbase >> 9;
  const float* bias = (MODE == 0) ? b0 : (seg == 0 ? b0 : (seg == 1 ? b1 : b2));
  u16* dstR = (seg == 0) ? C0 : C1;     // rowmajor dest (seg<2)
  #pragma unroll
  for (int j = 0; j < 4; ++j) {
    const int lc = (colbase & 511) + j*16 + cl;
    const float bb = bias[lc];
    #pragma unroll
    for (int i = 0; i < 4; ++i) {
      const int rbase = m0 + wm + i*16 + rq;
      float v[4];
      #pragma unroll
      for (int r = 0; r < 4; ++r) {
        float t = acc[i][j][r] + bb;
        if (MODE == 2 && seg == 0) t = 1.0f / (1.0f + __expf(-t));
        v[r] = t;
      }
      if (MODE == 1 && seg == 2) {
        uint2 o2;
        o2.x = pk2(v[0], v[1]); o2.y = pk2(v[2], v[3]);
        *(uint2*)(C2 + (size_t)lc*NTOK + rbase) = o2;
      } else {
        #pragma unroll
        for (int r = 0; r < 4; ++r)
          dstR[(size_t)(rbase + r)*DD + lc] = f2u(v[r]);
      }
    }
  }
}

// ---------------------------------------------------------------------------
// MFMA flash attention (round-8 proven version): S^T formulation, no-max
// softmax, LDS P round-trip, default launch bounds (no VGPR cap -> no spill).
// Block = (b, window n, head); 4 waves x 64 queries.
// Keys [(n-1)*W,(n+1)*W); n==0 -> only [0,W).
// vt input dim-major [512][NTOK] (written transposed by the V-GEMM epilogue).
// ---------------------------------------------------------------------------
#define EXPSC 0.18033688f   // 0.125 * log2(e)
__global__ __launch_bounds__(256) void attn_kernel(
    const u16* __restrict__ q, const u16* __restrict__ k,
    const u16* __restrict__ vt, u16* __restrict__ ctx)
{
  __shared__ u16 Ks[128*72];
  __shared__ u16 Vl[64*136];
  __shared__ u16 Ps[4*64*72];
  const int bid  = blockIdx.x;
  const int head = bid & 7;
  const int n    = (bid >> 3) & 31;
  const int b    = bid >> 8;
  const int tid  = threadIdx.x;
  const int lane = tid & 63;
  const int wave = tid >> 6;
  const int cl   = lane & 15;
  const int quad = lane >> 4;
  const int qtok0 = b*SEQ + n*WINSZ + wave*64;
  u16* Psw = Ps + wave*64*72;

  // Q fragments (B-operand: n=q rows, k-contiguous)
  bf16x8 qf[4][2];
  #pragma unroll
  for (int jf = 0; jf < 4; ++jf)
    #pragma unroll
    for (int kh = 0; kh < 2; ++kh)
      qf[jf][kh] = *(const bf16x8*)(q + (size_t)(qtok0 + jf*16 + cl)*DD
                                      + head*HDIM + kh*32 + quad*8);

  f32x4 oacc[4][4];   // [jd][jq]
  #pragma unroll
  for (int i = 0; i < 4; ++i)
    #pragma unroll
    for (int j = 0; j < 4; ++j)
      oacc[i][j] = (f32x4){0.f, 0.f, 0.f, 0.f};
  float lrun[4] = {0.f, 0.f, 0.f, 0.f};

  const int r0 = (n == 0) ? WINSZ : 0;
  const int base_tok = b*SEQ + (n - 1)*WINSZ;
  const int ksr = tid >> 1;          // K stage: key row 0..127
  const int ksc = (tid & 1) * 32;    // 64 B per thread
  const int vsr = tid >> 2;          // V stage: dim row 0..63
  const int vsc = (tid & 3) * 32;    // 64 B per thread

  for (int c0 = r0; c0 < 2*WINSZ; c0 += 128) {
    // ---- stage K [128 keys][64 d] and V^T [64 d][128 keys], 64 B/thread ----
    {
      const u16* ksrc = k + (size_t)(base_tok + c0 + ksr)*DD + head*HDIM + ksc;
      uint4* kd = (uint4*)(Ks + ksr*72 + ksc);
      kd[0] = ((const uint4*)ksrc)[0];
      kd[1] = ((const uint4*)ksrc)[1];
      kd[2] = ((const uint4*)ksrc)[2];
      kd[3] = ((const uint4*)ksrc)[3];
      const u16* vsrc = vt + (size_t)(head*HDIM + vsr)*NTOK + base_tok + c0 + vsc;
      uint4* vd = (uint4*)(Vl + vsr*136 + vsc);
      vd[0] = ((const uint4*)vsrc)[0];
      vd[1] = ((const uint4*)vsrc)[1];
      vd[2] = ((const uint4*)vsrc)[2];
      vd[3] = ((const uint4*)vsrc)[3];
    }
    __syncthreads();
    #pragma unroll
    for (int half = 0; half < 2; ++half) {
      // ---- S^T = K·Q^T : D[key][q] ----
      bf16x8 kf[4][2];
      #pragma unroll
      for (int i = 0; i < 4; ++i)
        #pragma unroll
        for (int kh = 0; kh < 2; ++kh)
          kf[i][kh] = *(const bf16x8*)(Ks + (half*64 + i*16 + cl)*72
                                          + kh*32 + quad*8);
      f32x4 sacc[4][4];
      #pragma unroll
      for (int i = 0; i < 4; ++i)
        #pragma unroll
        for (int jf = 0; jf < 4; ++jf) {
          f32x4 s = (f32x4){0.f, 0.f, 0.f, 0.f};
          s = __builtin_amdgcn_mfma_f32_16x16x32_bf16(kf[i][0], qf[jf][0], s, 0, 0, 0);
          s = __builtin_amdgcn_mfma_f32_16x16x32_bf16(kf[i][1], qf[jf][1], s, 0, 0, 0);
          sacc[i][jf] = s;
        }
      // ---- softmax numerators (no max subtraction), P scatter ----
      #pragma unroll
      for (int jf = 0; jf < 4; ++jf) {
        float rs = 0.f;
        #pragma unroll
        for (int i = 0; i < 4; ++i) {
          const float p0 = exp2f(sacc[i][jf][0] * EXPSC);
          const float p1 = exp2f(sacc[i][jf][1] * EXPSC);
          const float p2 = exp2f(sacc[i][jf][2] * EXPSC);
          const float p3 = exp2f(sacc[i][jf][3] * EXPSC);
          rs += (p0 + p1) + (p2 + p3);
          uint2 w;
          w.x = pk2(p0, p1); w.y = pk2(p2, p3);
          *(uint2*)(Psw + (jf*16 + cl)*72 + i*16 + quad*4) = w;
        }
        rs += __shfl_xor(rs, 16, 64);
        rs += __shfl_xor(rs, 32, 64);
        lrun[jf] += rs;
      }
      // ---- O^T += V^T·P : D[d][q]  (same-wave LDS ordering; no barrier) ----
      #pragma unroll
      for (int kh = 0; kh < 2; ++kh) {
        bf16x8 vf[4], pf[4];
        #pragma unroll
        for (int jd = 0; jd < 4; ++jd)
          vf[jd] = *(const bf16x8*)(Vl + (jd*16 + cl)*136
                                       + half*64 + kh*32 + quad*8);
        #pragma unroll
        for (int jq = 0; jq < 4; ++jq)
          pf[jq] = *(const bf16x8*)(Psw + (jq*16 + cl)*72 + kh*32 + quad*8);
        #pragma unroll
        for (int jd = 0; jd < 4; ++jd)
          #pragma unroll
          for (int jq = 0; jq < 4; ++jq)
            oacc[jd][jq] = __builtin_amdgcn_mfma_f32_16x16x32_bf16(
                vf[jd], pf[jq], oacc[jd][jq], 0, 0, 0);
      }
    }
    __syncthreads();
  }
  // ---- epilogue: per lane q = jq*16+cl, dims jd*16+quad*4+r (8B stores) ----
  #pragma unroll
  for (int jq = 0; jq < 4; ++jq) {
    const float inv = 1.0f / lrun[jq];
    u16* crow = ctx + (size_t)(qtok0 + jq*16 + cl)*DD + head*HDIM + quad*4;
    #pragma unroll
    for (int jd = 0; jd < 4; ++jd) {
      uint2 o2;
      o2.x = pk2(oacc[jd][jq][0]*inv, oacc[jd][jq][1]*inv);
      o2.y = pk2(oacc[jd][jq][2]*inv, oacc[jd][jq][3]*inv);
      *(uint2*)(crow + jd*16) = o2;
    }
  }
}

// ---------------------------------------------------------------------------
// new_mem = g*u + (1-g)*mem ; h = LN(a + new_mem)  (wave per token)
// ---------------------------------------------------------------------------
__global__ __launch_bounds__(256) void memln_kernel(
    const u16* __restrict__ a, const u16* __restrict__ gate, const u16* __restrict__ upd,
    u16* __restrict__ mem, const float* __restrict__ lg, const float* __restrict__ lb,
    u16* __restrict__ h)
{
  const int lane = threadIdx.x & 63;
  const int wave = threadIdx.x >> 6;
  const int t = blockIdx.x*4 + wave;
  const size_t base = (size_t)t*DD + lane*8;
  float av[8], gv[8], uv[8], mv[8];
  ld8(a + base, av); ld8(gate + base, gv); ld8(upd + base, uv); ld8(mem + base, mv);
  float s[8], nm[8], sum = 0.f, sq = 0.f;
  #pragma unroll
  for (int e = 0; e < 8; ++e) {
    nm[e] = gv[e]*uv[e] + (1.0f - gv[e])*mv[e];
    s[e]  = av[e] + nm[e];
    sum  += s[e]; sq += s[e]*s[e];
  }
  st8(mem + base, nm);
  for (int o = 32; o > 0; o >>= 1) {
    sum += __shfl_xor(sum, o, 64);
    sq  += __shfl_xor(sq,  o, 64);
  }
  const float mean = sum * (1.0f/512.0f);
  const float var  = sq  * (1.0f/512.0f) - mean*mean;
  const float r = rsqrtf(var + 1e-5f);
  float y[8];
  #pragma unroll
  for (int e = 0; e < 8; ++e) {
    const int ch = lane*8 + e;
    y[e] = (s[e] - mean)*r*lg[ch] + lb[ch];
  }
  st8(h + base, y);
}

// ---------------------------------------------------------------------------
// final: o = LN(LN(c, cn), on) ; out = o @ W_out + b_out  (fp32 out)
// ---------------------------------------------------------------------------
__global__ __launch_bounds__(256) void final_kernel(
    const u16* __restrict__ c,
    const float* __restrict__ cng, const float* __restrict__ cnb,
    const float* __restrict__ ong, const float* __restrict__ onb,
    const float* __restrict__ Wout, const float* __restrict__ bout,
    float* __restrict__ out)
{
  __shared__ float ybuf[4][512];
  const int lane = threadIdx.x & 63;
  const int wave = threadIdx.x >> 6;
  const int t = blockIdx.x*4 + wave;
  const size_t base = (size_t)t*DD + lane*8;
  float x[8];
  ld8(c + base, x);
  float sum = 0.f, sq = 0.f;
  #pragma unroll
  for (int e = 0; e < 8; ++e) { sum += x[e]; sq += x[e]*x[e]; }
  for (int o = 32; o > 0; o >>= 1) { sum += __shfl_xor(sum, o, 64); sq += __shfl_xor(sq, o, 64); }
  float mean = sum * (1.0f/512.0f);
  float var  = sq  * (1.0f/512.0f) - mean*mean;
  float r = rsqrtf(var + 1e-5f);
  float y[8];
  float sum2 = 0.f, sq2 = 0.f;
  #pragma unroll
  for (int e = 0; e < 8; ++e) {
    const int ch = lane*8 + e;
    y[e] = (x[e] - mean)*r*cng[ch] + cnb[ch];
    sum2 += y[e]; sq2 += y[e]*y[e];
  }
  for (int o = 32; o > 0; o >>= 1) { sum2 += __shfl_xor(sum2, o, 64); sq2 += __shfl_xor(sq2, o, 64); }
  mean = sum2 * (1.0f/512.0f);
  var  = sq2  * (1.0f/512.0f) - mean*mean;
  r = rsqrtf(var + 1e-5f);
  #pragma unroll
  for (int e = 0; e < 8; ++e) {
    const int ch = lane*8 + e;
    ybuf[wave][ch] = (y[e] - mean)*r*ong[ch] + onb[ch];
  }
  __syncthreads();
  if (lane < FF) {
    float acc = bout[lane];
    for (int ch = 0; ch < 512; ++ch)
      acc += ybuf[wave][ch] * Wout[ch*FF + lane];
    out[(size_t)t*FF + lane] = acc;
  }
}

// ---------------------------------------------------------------------------
// Workspace (164 MB):
//   mem @0 (32MB persistent bf16), B1 @32MB, B2 @64MB, B3 @96MB, B4 @128MB,
//   WB @160MB (4MB: per-layer transposed bf16 weights / W_emb^T / conv W^T)
// ---------------------------------------------------------------------------
extern "C" void kernel_launch(void* const* d_in, const int* in_sizes, int n_in,
                              void* d_out, int out_size, void* d_ws, size_t ws_size,
                              hipStream_t stream)
{
  const float* x      = (const float*)d_in[0];
  const int*   tstamp = (const int*)d_in[1];
  const float* W_feat = (const float*)d_in[2];
  const float* b_feat = (const float*)d_in[3];
  const float* emb_t  = (const float*)d_in[4];
  const float* W_emb  = (const float*)d_in[5];
  const float* b_emb  = (const float*)d_in[6];
  const float* Wq = (const float*)d_in[7];   const float* bq = (const float*)d_in[8];
  const float* Wk = (const float*)d_in[9];   const float* bk = (const float*)d_in[10];
  const float* Wv = (const float*)d_in[11];  const float* bv = (const float*)d_in[12];
  const float* Wo = (const float*)d_in[13];  const float* bo = (const float*)d_in[14];
  const float* Wg = (const float*)d_in[15];  const float* bg = (const float*)d_in[16];
  const float* Wu = (const float*)d_in[17];  const float* bu = (const float*)d_in[18];
  const float* lng = (const float*)d_in[19]; const float* lnb = (const float*)d_in[20];
  const float* convw = (const float*)d_in[21]; const float* convb = (const float*)d_in[22];
  const float* cng = (const float*)d_in[23]; const float* cnb = (const float*)d_in[24];
  const float* ong = (const float*)d_in[25]; const float* onb = (const float*)d_in[26];
  const float* Wout = (const float*)d_in[27]; const float* bout = (const float*)d_in[28];
  float* outp = (float*)d_out;

  char* ws = (char*)d_ws;
  const size_t MB = 1024u*1024u;
  u16* mem = (u16*)ws;
  u16* B1  = (u16*)(ws + 32*MB);
  u16* B2  = (u16*)(ws + 64*MB);
  u16* B3  = (u16*)(ws + 96*MB);
  u16* B4  = (u16*)(ws + 128*MB);
  u16* WB  = (u16*)(ws + 160*MB);

  hipMemsetAsync(mem, 0, (size_t)NTOK*DD*sizeof(u16), stream);

  // Embedding: cat -> B2 ; W_emb^T -> WB ; h -> B1
  embed_kernel<<<NTOK, 128, 0, stream>>>(x, tstamp, W_feat, b_feat, emb_t, B2);
  transpose_w<<<dim3(8, 16), 256, 0, stream>>>(W_emb, WB, 256);
  mfma_gemm<0><<<dim3(4, NTOK/128), 256, 0, stream>>>(
      B2, B2, 256, 256, WB, b_emb, nullptr, nullptr, B1, nullptr, nullptr);

  for (int l = 0; l < LAYERS; ++l) {
    convert_layer<<<dim3(32, 16, 6), 256, 0, stream>>>(
        Wq + (size_t)l*DD*DD, Wk + (size_t)l*DD*DD, Wv + (size_t)l*DD*DD,
        Wo + (size_t)l*DD*DD, Wg + (size_t)l*2*DD*DD, Wu + (size_t)l*2*DD*DD, WB);
    // fused qkv: q -> B2, k -> B3, v^T -> B4
    mfma_gemm<1><<<dim3(12, NTOK/128), 256, 0, stream>>>(
        B1, B1, 512, 512, WB + WQO,
        bq + l*DD, bk + l*DD, bv + l*DD, B2, B3, B4);
    // ctx -> B1 (h dead)
    attn_kernel<<<BATCH*NBLK*HEADS, 256, 0, stream>>>(B2, B3, B4, B1);
    // a = ctx @ Wo + bo -> B2
    mfma_gemm<0><<<dim3(4, NTOK/128), 256, 0, stream>>>(
        B1, B1, 512, 512, WB + WOO, bo + l*DD, nullptr, nullptr,
        B2, nullptr, nullptr);
    // fused gate/upd: gate -> B3 (sigmoid), upd -> B4
    mfma_gemm<2><<<dim3(8, NTOK/128), 256, 0, stream>>>(
        B2, mem, 512, 1024, WB + WGO,
        bg + l*DD, bu + l*DD, nullptr, B3, B4, nullptr);
    // mem update + LN -> h (B1)
    memln_kernel<<<NTOK/4, 256, 0, stream>>>(
        B2, B3, B4, mem, lng + l*DD, lnb + l*DD, B1);
  }

  // Temporal conv as GEMM: A = h [8192, 2048]; conv W^T -> WB; c -> B3
  repack_conv<<<4096, 256, 0, stream>>>(convw, WB);
  mfma_gemm<0><<<dim3(4, 8192/128), 256, 0, stream>>>(
      B1, B1, 2048, 2048, WB, convb, nullptr, nullptr, B3, nullptr, nullptr);

  // LN -> LN -> out projection (fp32 out)
  final_kernel<<<8192/4, 256, 0, stream>>>(
      B3, cng, cnb, ong, onb, Wout, bout, outp);
}

// Round 11
// 1582.716 us; speedup vs baseline: 1.4891x; 1.1217x over previous
//
#include <hip/hip_runtime.h>

// Problem constants
#define BATCH   4
#define SEQ     8192
#define NTOK    32768      // BATCH*SEQ
#define FF      32
#define FDIM    128
#define DD      512
#define HEADS   8
#define HDIM    64
#define WINSZ   256
#define NBLK    32         // SEQ/WINSZ
#define LAYERS  4

typedef unsigned short u16;
typedef __attribute__((ext_vector_type(8))) short bf16x8;
typedef __attribute__((ext_vector_type(4))) float f32x4;

__device__ __forceinline__ float u2f(u16 u) {
  return __uint_as_float(((unsigned int)u) << 16);
}
// round-half-up bf16 (2 VALU ops)
__device__ __forceinline__ u16 f2u(float f) {
  return (u16)((__float_as_uint(f) + 0x8000u) >> 16);
}
__device__ __forceinline__ unsigned int pk2(float a, float b) {
  return ((__float_as_uint(a) + 0x8000u) >> 16) |
         ((__float_as_uint(b) + 0x8000u) & 0xffff0000u);
}
__device__ __forceinline__ void ld8(const u16* __restrict__ p, float* o) {
  ushort4 q0 = *(const ushort4*)p;
  ushort4 q1 = *(const ushort4*)(p + 4);
  o[0]=u2f(q0.x); o[1]=u2f(q0.y); o[2]=u2f(q0.z); o[3]=u2f(q0.w);
  o[4]=u2f(q1.x); o[5]=u2f(q1.y); o[6]=u2f(q1.z); o[7]=u2f(q1.w);
}
__device__ __forceinline__ void st8(u16* __restrict__ p, const float* v) {
  uint4 o;
  o.x = pk2(v[0], v[1]); o.y = pk2(v[2], v[3]);
  o.z = pk2(v[4], v[5]); o.w = pk2(v[6], v[7]);
  *(uint4*)p = o;
}
// async global->LDS, 16B per lane; LDS dest = wave-uniform base + lane*16
__device__ __forceinline__ void gl_lds16(const u16* g, u16* l) {
  __builtin_amdgcn_global_load_lds(
      (const __attribute__((address_space(1))) void*)g,
      (__attribute__((address_space(3))) void*)l, 16, 0, 0);
}

// ---------------------------------------------------------------------------
// Embedding: fe = x@W_feat + b_feat ; cat = [fe, emb_temp[ts]]
// ---------------------------------------------------------------------------
__global__ __launch_bounds__(128) void embed_kernel(
    const float* __restrict__ x, const int* __restrict__ ts,
    const float* __restrict__ W_feat, const float* __restrict__ b_feat,
    const float* __restrict__ emb, u16* __restrict__ cat)
{
  const int t = blockIdx.x;
  const int j = threadIdx.x;   // 0..127
  __shared__ float xs[FF];
  if (j < FF) xs[j] = x[(size_t)t*FF + j];
  __syncthreads();
  float fe = b_feat[j];
  #pragma unroll
  for (int f = 0; f < FF; ++f) fe += xs[f] * W_feat[f*FDIM + j];
  cat[(size_t)t*256 + j] = f2u(fe);
  const int tv = ts[t];
  cat[(size_t)t*256 + 128 + j] = f2u(emb[(size_t)tv*FDIM + j]);
}

// ---------------------------------------------------------------------------
// Weight transpose+convert: src fp32 [K][512] -> dst bf16 [512][K]
// ---------------------------------------------------------------------------
__global__ __launch_bounds__(256) void transpose_w(
    const float* __restrict__ src, u16* __restrict__ dst, int K)
{
  __shared__ u16 t[32][34];
  const int bk = blockIdx.x*32, bn = blockIdx.y*32;
  const int c = threadIdx.x & 31, r8 = threadIdx.x >> 5;
  #pragma unroll
  for (int rr = 0; rr < 32; rr += 8)
    t[rr + r8][c] = f2u(src[(size_t)(bk + rr + r8)*512 + bn + c]);
  __syncthreads();
  #pragma unroll
  for (int rr = 0; rr < 32; rr += 8)
    dst[(size_t)(bn + rr + r8)*K + bk + c] = t[c][rr + r8];
}

// Weight slot offsets (u16 elements) within the per-layer buffer
#define WQO 0
#define WKO 262144
#define WVO 524288
#define WOO 786432
#define WGO 1048576
#define WUO 1572864

__global__ __launch_bounds__(256) void convert_layer(
    const float* __restrict__ Wq, const float* __restrict__ Wk,
    const float* __restrict__ Wv, const float* __restrict__ Wo,
    const float* __restrict__ Wg, const float* __restrict__ Wu,
    u16* __restrict__ out)
{
  __shared__ u16 t[32][34];
  const int z = blockIdx.z;
  const int K = (z < 4) ? 512 : 1024;
  const int bk = blockIdx.x*32;
  if (bk >= K) return;
  const int bn = blockIdx.y*32;
  const float* src = (z==0)?Wq:(z==1)?Wk:(z==2)?Wv:(z==3)?Wo:(z==4)?Wg:Wu;
  u16* dst = out + ((z<4) ? (size_t)z*262144 : (size_t)1048576 + (size_t)(z-4)*524288);
  const int c = threadIdx.x & 31, r8 = threadIdx.x >> 5;
  #pragma unroll
  for (int rr = 0; rr < 32; rr += 8)
    t[rr + r8][c] = f2u(src[(size_t)(bk + rr + r8)*512 + bn + c]);
  __syncthreads();
  #pragma unroll
  for (int rr = 0; rr < 32; rr += 8)
    dst[(size_t)(bn + rr + r8)*K + bk + c] = t[c][rr + r8];
}

// conv_w fp32 [o,ch,j] -> bf16 [o][k=j*512+ch]  (transposed-B GEMM-ready)
__global__ __launch_bounds__(256) void repack_conv(
    const float* __restrict__ cw, u16* __restrict__ dst)
{
  const int t = blockIdx.x*256 + threadIdx.x;     // < 512*2048
  const int o  = t >> 11;
  const int kk = t & 2047;
  const int j  = kk >> 9;
  const int ch = kk & 511;
  dst[t] = f2u(cw[(size_t)o*2048 + ch*4 + j]);
}

// ---------------------------------------------------------------------------
// MFMA GEMM v2: BM=128, BN=256, BK=32, 512 threads = 8 waves (64x64 each).
// XCD-aware swizzle: consecutive same-XCD blocks sweep the column tiles of
// one row-block -> A row-tile served from that XCD's L2 (needs gridY%8==0).
// MODE 0: C0 = A@B + b0 (rowmajor [M][512])
// MODE 1: qkv fused N=1536: seg0->C0(q), seg1->C1(k) rowmajor; seg2->C2(v^T)
// MODE 2: gate/upd fused N=1024: seg0->sigmoid->C0, seg1->C1 (rowmajor)
// A bf16 dual-source (concat), Bt bf16 [N][K], fp32 accum.
// ---------------------------------------------------------------------------
template<int MODE>
__global__ __launch_bounds__(512) void mfma_gemm(
    const u16* __restrict__ A1, const u16* __restrict__ A2, int K1, int K,
    const u16* __restrict__ Bt,
    const float* __restrict__ b0, const float* __restrict__ b1,
    const float* __restrict__ b2,
    u16* __restrict__ C0, u16* __restrict__ C1, u16* __restrict__ C2)
{
  __shared__ u16 Al[128*32];    // 8 KB
  __shared__ u16 Bl[256*32];    // 16 KB
  const int tid  = threadIdx.x;
  const int lane = tid & 63;
  const int wave = tid >> 6;          // 0..7
  const int wm = (wave & 1) * 64;
  const int wn = (wave >> 1) * 64;    // 0..192
  // XCD swizzle
  const int bid = blockIdx.x + gridDim.x * blockIdx.y;
  const int xcd = bid & 7;
  const int jj  = bid >> 3;
  const int nx  = jj % gridDim.x;
  const int my  = (jj / gridDim.x) * 8 + xcd;
  const int m0 = my * 128;
  const int n0 = nx * 256;
  const int cl = lane & 15, quad = lane >> 4;
  const int arow = tid >> 2;          // 0..127
  const int ak   = (tid & 3) * 8;
  u16* Adst  = Al + wave*512;         // HW adds lane*16B
  u16* Bdst0 = Bl + wave*512;
  u16* Bdst1 = Bl + 4096 + wave*512;
  const int K2 = K - K1;

  f32x4 acc[4][4];
  #pragma unroll
  for (int i = 0; i < 4; ++i)
    #pragma unroll
    for (int j = 0; j < 4; ++j)
      acc[i][j] = (f32x4){0.f, 0.f, 0.f, 0.f};

  for (int k0 = 0; k0 < K; k0 += 32) {
    const int kc = k0 + ak;
    const u16* a = (kc < K1) ? A1 + (size_t)(m0 + arow)*K1 + kc
                             : A2 + (size_t)(m0 + arow)*K2 + (kc - K1);
    gl_lds16(a, Adst);
    gl_lds16(Bt + (size_t)(n0 + arow)*K + kc,       Bdst0);
    gl_lds16(Bt + (size_t)(n0 + 128 + arow)*K + kc, Bdst1);
    __syncthreads();
    bf16x8 af[4], bfr[4];
    #pragma unroll
    for (int i = 0; i < 4; ++i) {
      af[i]  = *(const bf16x8*)(Al + (wm + i*16 + cl)*32 + quad*8);
      bfr[i] = *(const bf16x8*)(Bl + (wn + i*16 + cl)*32 + quad*8);
    }
    #pragma unroll
    for (int i = 0; i < 4; ++i)
      #pragma unroll
      for (int j = 0; j < 4; ++j)
        acc[i][j] = __builtin_amdgcn_mfma_f32_16x16x32_bf16(
            af[i], bfr[j], acc[i][j], 0, 0, 0);
    __syncthreads();
  }
  const int rq = quad * 4;
  const int colbase = n0 + wn;          // 64-aligned -> seg uniform per wave
  const int seg = colbase >> 9;
  const float* bias = (MODE == 0) ? b0 : (seg == 0 ? b0 : (seg == 1 ? b1 : b2));
  u16* dstR = (seg == 0) ? C0 : C1;     // rowmajor dest (seg<2)
  #pragma unroll
  for (int j = 0; j < 4; ++j) {
    const int lc = (colbase & 511) + j*16 + cl;
    const float bb = bias[lc];
    #pragma unroll
    for (int i = 0; i < 4; ++i) {
      const int rbase = m0 + wm + i*16 + rq;
      float v[4];
      #pragma unroll
      for (int r = 0; r < 4; ++r) {
        float t = acc[i][j][r] + bb;
        if (MODE == 2 && seg == 0) t = 1.0f / (1.0f + __expf(-t));
        v[r] = t;
      }
      if (MODE == 1 && seg == 2) {
        uint2 o2;
        o2.x = pk2(v[0], v[1]); o2.y = pk2(v[2], v[3]);
        *(uint2*)(C2 + (size_t)lc*NTOK + rbase) = o2;
      } else {
        #pragma unroll
        for (int r = 0; r < 4; ++r)
          dstR[(size_t)(rbase + r)*DD + lc] = f2u(v[r]);
      }
    }
  }
}

// ---------------------------------------------------------------------------
// MFMA flash attention: S^T formulation, no-max softmax, shuffle-based P
// (no LDS P buffer -> 35.8 KB LDS). DEFAULT launch bounds: round 9 showed a
// forced waves-per-EU cap (256,3) caps VGPR at 84 -> scratch spill (WRITE
// 495 MB, 2.3x slower). Uncapped the body needs no spill.
// Block = (b, window n, head); 4 waves x 64 queries.
// Keys [(n-1)*W,(n+1)*W); n==0 -> only [0,W).
// P B-operand fragments built in-register from S^T C-layout via __shfl:
//   dest (cl,quad,j): i=2kh+(quad>>1), quad'=2(quad&1)+(j>>2), r=j&3,
//   src lane = cl + 16*quad'.
// vt input dim-major [512][NTOK] (written transposed by the V-GEMM epilogue).
// ---------------------------------------------------------------------------
#define EXPSC 0.18033688f   // 0.125 * log2(e)
__global__ __launch_bounds__(256) void attn_kernel(
    const u16* __restrict__ q, const u16* __restrict__ k,
    const u16* __restrict__ vt, u16* __restrict__ ctx)
{
  __shared__ u16 Ks[128*72];
  __shared__ u16 Vl[64*136];
  const int bid  = blockIdx.x;
  const int head = bid & 7;
  const int n    = (bid >> 3) & 31;
  const int b    = bid >> 8;
  const int tid  = threadIdx.x;
  const int lane = tid & 63;
  const int wave = tid >> 6;
  const int cl   = lane & 15;
  const int quad = lane >> 4;
  const int qtok0 = b*SEQ + n*WINSZ + wave*64;
  const bool hi2 = (lane >= 32);              // quad>=2 -> use sacc[2kh+1]
  const int srcA = cl + ((quad & 1) << 5);    // lane of quad' = 2(quad&1)
  const int srcB = srcA + 16;                 // lane of quad' = 2(quad&1)+1

  // Q fragments (B-operand: n=q rows, k-contiguous)
  bf16x8 qf[4][2];
  #pragma unroll
  for (int jf = 0; jf < 4; ++jf)
    #pragma unroll
    for (int kh = 0; kh < 2; ++kh)
      qf[jf][kh] = *(const bf16x8*)(q + (size_t)(qtok0 + jf*16 + cl)*DD
                                      + head*HDIM + kh*32 + quad*8);

  f32x4 oacc[4][4];   // [jd][jq]
  #pragma unroll
  for (int i = 0; i < 4; ++i)
    #pragma unroll
    for (int j = 0; j < 4; ++j)
      oacc[i][j] = (f32x4){0.f, 0.f, 0.f, 0.f};
  float lrun[4] = {0.f, 0.f, 0.f, 0.f};

  const int r0 = (n == 0) ? WINSZ : 0;
  const int base_tok = b*SEQ + (n - 1)*WINSZ;
  const int ksr = tid >> 1;          // K stage: key row 0..127
  const int ksc = (tid & 1) * 32;    // 64 B per thread
  const int vsr = tid >> 2;          // V stage: dim row 0..63
  const int vsc = (tid & 3) * 32;    // 64 B per thread

  for (int c0 = r0; c0 < 2*WINSZ; c0 += 128) {
    // ---- stage K [128 keys][64 d] and V^T [64 d][128 keys], 64 B/thread ----
    {
      const u16* ksrc = k + (size_t)(base_tok + c0 + ksr)*DD + head*HDIM + ksc;
      uint4* kd = (uint4*)(Ks + ksr*72 + ksc);
      kd[0] = ((const uint4*)ksrc)[0];
      kd[1] = ((const uint4*)ksrc)[1];
      kd[2] = ((const uint4*)ksrc)[2];
      kd[3] = ((const uint4*)ksrc)[3];
      const u16* vsrc = vt + (size_t)(head*HDIM + vsr)*NTOK + base_tok + c0 + vsc;
      uint4* vd = (uint4*)(Vl + vsr*136 + vsc);
      vd[0] = ((const uint4*)vsrc)[0];
      vd[1] = ((const uint4*)vsrc)[1];
      vd[2] = ((const uint4*)vsrc)[2];
      vd[3] = ((const uint4*)vsrc)[3];
    }
    __syncthreads();
    #pragma unroll
    for (int half = 0; half < 2; ++half) {
      #pragma unroll
      for (int jf = 0; jf < 4; ++jf) {
        // ---- S^T = K·Q^T for this jf: sa[i] = D[key 16i+4quad+r][q 16jf+cl]
        f32x4 sa[4];
        #pragma unroll
        for (int i = 0; i < 4; ++i) {
          const u16* kr = Ks + (half*64 + i*16 + cl)*72 + quad*8;
          bf16x8 k0 = *(const bf16x8*)kr;
          bf16x8 k1 = *(const bf16x8*)(kr + 32);
          f32x4 s = (f32x4){0.f, 0.f, 0.f, 0.f};
          s = __builtin_amdgcn_mfma_f32_16x16x32_bf16(k0, qf[jf][0], s, 0, 0, 0);
          s = __builtin_amdgcn_mfma_f32_16x16x32_bf16(k1, qf[jf][1], s, 0, 0, 0);
          sa[i] = s;
        }
        // ---- softmax numerators (no max), pack to bf16 pairs ----
        float rs = 0.f;
        unsigned int pd[4][2];
        #pragma unroll
        for (int i = 0; i < 4; ++i) {
          const float p0 = exp2f(sa[i][0] * EXPSC);
          const float p1 = exp2f(sa[i][1] * EXPSC);
          const float p2 = exp2f(sa[i][2] * EXPSC);
          const float p3 = exp2f(sa[i][3] * EXPSC);
          rs += (p0 + p1) + (p2 + p3);
          pd[i][0] = pk2(p0, p1);
          pd[i][1] = pk2(p2, p3);
        }
        rs += __shfl_xor(rs, 16, 64);
        rs += __shfl_xor(rs, 32, 64);
        lrun[jf] += rs;
        // ---- build P B-frags via shuffles, PV MFMA ----
        #pragma unroll
        for (int kh = 0; kh < 2; ++kh) {
          const int aA0 = __shfl((int)pd[2*kh][0],   srcA, 64);
          const int aB0 = __shfl((int)pd[2*kh+1][0], srcA, 64);
          const int aA1 = __shfl((int)pd[2*kh][1],   srcA, 64);
          const int aB1 = __shfl((int)pd[2*kh+1][1], srcA, 64);
          const int cA0 = __shfl((int)pd[2*kh][0],   srcB, 64);
          const int cB0 = __shfl((int)pd[2*kh+1][0], srcB, 64);
          const int cA1 = __shfl((int)pd[2*kh][1],   srcB, 64);
          const int cB1 = __shfl((int)pd[2*kh+1][1], srcB, 64);
          uint4 pw;
          pw.x = hi2 ? aB0 : aA0;
          pw.y = hi2 ? aB1 : aA1;
          pw.z = hi2 ? cB0 : cA0;
          pw.w = hi2 ? cB1 : cA1;
          bf16x8 pf = *(bf16x8*)&pw;
          #pragma unroll
          for (int jd = 0; jd < 4; ++jd) {
            bf16x8 vf = *(const bf16x8*)(Vl + (jd*16 + cl)*136
                                            + half*64 + kh*32 + quad*8);
            oacc[jd][jf] = __builtin_amdgcn_mfma_f32_16x16x32_bf16(
                vf, pf, oacc[jd][jf], 0, 0, 0);
          }
        }
      }
    }
    __syncthreads();
  }
  // ---- epilogue: per lane q = jq*16+cl, dims jd*16+quad*4+r (8B stores) ----
  #pragma unroll
  for (int jq = 0; jq < 4; ++jq) {
    const float inv = 1.0f / lrun[jq];
    u16* crow = ctx + (size_t)(qtok0 + jq*16 + cl)*DD + head*HDIM + quad*4;
    #pragma unroll
    for (int jd = 0; jd < 4; ++jd) {
      uint2 o2;
      o2.x = pk2(oacc[jd][jq][0]*inv, oacc[jd][jq][1]*inv);
      o2.y = pk2(oacc[jd][jq][2]*inv, oacc[jd][jq][3]*inv);
      *(uint2*)(crow + jd*16) = o2;
    }
  }
}

// ---------------------------------------------------------------------------
// new_mem = g*u + (1-g)*mem ; h = LN(a + new_mem)  (wave per token)
// ---------------------------------------------------------------------------
__global__ __launch_bounds__(256) void memln_kernel(
    const u16* __restrict__ a, const u16* __restrict__ gate, const u16* __restrict__ upd,
    u16* __restrict__ mem, const float* __restrict__ lg, const float* __restrict__ lb,
    u16* __restrict__ h)
{
  const int lane = threadIdx.x & 63;
  const int wave = threadIdx.x >> 6;
  const int t = blockIdx.x*4 + wave;
  const size_t base = (size_t)t*DD + lane*8;
  float av[8], gv[8], uv[8], mv[8];
  ld8(a + base, av); ld8(gate + base, gv); ld8(upd + base, uv); ld8(mem + base, mv);
  float s[8], nm[8], sum = 0.f, sq = 0.f;
  #pragma unroll
  for (int e = 0; e < 8; ++e) {
    nm[e] = gv[e]*uv[e] + (1.0f - gv[e])*mv[e];
    s[e]  = av[e] + nm[e];
    sum  += s[e]; sq += s[e]*s[e];
  }
  st8(mem + base, nm);
  for (int o = 32; o > 0; o >>= 1) {
    sum += __shfl_xor(sum, o, 64);
    sq  += __shfl_xor(sq,  o, 64);
  }
  const float mean = sum * (1.0f/512.0f);
  const float var  = sq  * (1.0f/512.0f) - mean*mean;
  const float r = rsqrtf(var + 1e-5f);
  float y[8];
  #pragma unroll
  for (int e = 0; e < 8; ++e) {
    const int ch = lane*8 + e;
    y[e] = (s[e] - mean)*r*lg[ch] + lb[ch];
  }
  st8(h + base, y);
}

// ---------------------------------------------------------------------------
// final: o = LN(LN(c, cn), on) ; out = o @ W_out + b_out  (fp32 out)
// ---------------------------------------------------------------------------
__global__ __launch_bounds__(256) void final_kernel(
    const u16* __restrict__ c,
    const float* __restrict__ cng, const float* __restrict__ cnb,
    const float* __restrict__ ong, const float* __restrict__ onb,
    const float* __restrict__ Wout, const float* __restrict__ bout,
    float* __restrict__ out)
{
  __shared__ float ybuf[4][512];
  const int lane = threadIdx.x & 63;
  const int wave = threadIdx.x >> 6;
  const int t = blockIdx.x*4 + wave;
  const size_t base = (size_t)t*DD + lane*8;
  float x[8];
  ld8(c + base, x);
  float sum = 0.f, sq = 0.f;
  #pragma unroll
  for (int e = 0; e < 8; ++e) { sum += x[e]; sq += x[e]*x[e]; }
  for (int o = 32; o > 0; o >>= 1) { sum += __shfl_xor(sum, o, 64); sq += __shfl_xor(sq, o, 64); }
  float mean = sum * (1.0f/512.0f);
  float var  = sq  * (1.0f/512.0f) - mean*mean;
  float r = rsqrtf(var + 1e-5f);
  float y[8];
  float sum2 = 0.f, sq2 = 0.f;
  #pragma unroll
  for (int e = 0; e < 8; ++e) {
    const int ch = lane*8 + e;
    y[e] = (x[e] - mean)*r*cng[ch] + cnb[ch];
    sum2 += y[e]; sq2 += y[e]*y[e];
  }
  for (int o = 32; o > 0; o >>= 1) { sum2 += __shfl_xor(sum2, o, 64); sq2 += __shfl_xor(sq2, o, 64); }
  mean = sum2 * (1.0f/512.0f);
  var  = sq2  * (1.0f/512.0f) - mean*mean;
  r = rsqrtf(var + 1e-5f);
  #pragma unroll
  for (int e = 0; e < 8; ++e) {
    const int ch = lane*8 + e;
    ybuf[wave][ch] = (y[e] - mean)*r*ong[ch] + onb[ch];
  }
  __syncthreads();
  if (lane < FF) {
    float acc = bout[lane];
    for (int ch = 0; ch < 512; ++ch)
      acc += ybuf[wave][ch] * Wout[ch*FF + lane];
    out[(size_t)t*FF + lane] = acc;
  }
}

// ---------------------------------------------------------------------------
// Workspace (164 MB):
//   mem @0 (32MB persistent bf16), B1 @32MB, B2 @64MB, B3 @96MB, B4 @128MB,
//   WB @160MB (4MB: per-layer transposed bf16 weights / W_emb^T / conv W^T)
// ---------------------------------------------------------------------------
extern "C" void kernel_launch(void* const* d_in, const int* in_sizes, int n_in,
                              void* d_out, int out_size, void* d_ws, size_t ws_size,
                              hipStream_t stream)
{
  const float* x      = (const float*)d_in[0];
  const int*   tstamp = (const int*)d_in[1];
  const float* W_feat = (const float*)d_in[2];
  const float* b_feat = (const float*)d_in[3];
  const float* emb_t  = (const float*)d_in[4];
  const float* W_emb  = (const float*)d_in[5];
  const float* b_emb  = (const float*)d_in[6];
  const float* Wq = (const float*)d_in[7];   const float* bq = (const float*)d_in[8];
  const float* Wk = (const float*)d_in[9];   const float* bk = (const float*)d_in[10];
  const float* Wv = (const float*)d_in[11];  const float* bv = (const float*)d_in[12];
  const float* Wo = (const float*)d_in[13];  const float* bo = (const float*)d_in[14];
  const float* Wg = (const float*)d_in[15];  const float* bg = (const float*)d_in[16];
  const float* Wu = (const float*)d_in[17];  const float* bu = (const float*)d_in[18];
  const float* lng = (const float*)d_in[19]; const float* lnb = (const float*)d_in[20];
  const float* convw = (const float*)d_in[21]; const float* convb = (const float*)d_in[22];
  const float* cng = (const float*)d_in[23]; const float* cnb = (const float*)d_in[24];
  const float* ong = (const float*)d_in[25]; const float* onb = (const float*)d_in[26];
  const float* Wout = (const float*)d_in[27]; const float* bout = (const float*)d_in[28];
  float* outp = (float*)d_out;

  char* ws = (char*)d_ws;
  const size_t MB = 1024u*1024u;
  u16* mem = (u16*)ws;
  u16* B1  = (u16*)(ws + 32*MB);
  u16* B2  = (u16*)(ws + 64*MB);
  u16* B3  = (u16*)(ws + 96*MB);
  u16* B4  = (u16*)(ws + 128*MB);
  u16* WB  = (u16*)(ws + 160*MB);

  hipMemsetAsync(mem, 0, (size_t)NTOK*DD*sizeof(u16), stream);

  // Embedding: cat -> B2 ; W_emb^T -> WB ; h -> B1
  embed_kernel<<<NTOK, 128, 0, stream>>>(x, tstamp, W_feat, b_feat, emb_t, B2);
  transpose_w<<<dim3(8, 16), 256, 0, stream>>>(W_emb, WB, 256);
  mfma_gemm<0><<<dim3(2, NTOK/128), 512, 0, stream>>>(
      B2, B2, 256, 256, WB, b_emb, nullptr, nullptr, B1, nullptr, nullptr);

  for (int l = 0; l < LAYERS; ++l) {
    convert_layer<<<dim3(32, 16, 6), 256, 0, stream>>>(
        Wq + (size_t)l*DD*DD, Wk + (size_t)l*DD*DD, Wv + (size_t)l*DD*DD,
        Wo + (size_t)l*DD*DD, Wg + (size_t)l*2*DD*DD, Wu + (size_t)l*2*DD*DD, WB);
    // fused qkv: q -> B2, k -> B3, v^T -> B4
    mfma_gemm<1><<<dim3(6, NTOK/128), 512, 0, stream>>>(
        B1, B1, 512, 512, WB + WQO,
        bq + l*DD, bk + l*DD, bv + l*DD, B2, B3, B4);
    // ctx -> B1 (h dead)
    attn_kernel<<<BATCH*NBLK*HEADS, 256, 0, stream>>>(B2, B3, B4, B1);
    // a = ctx @ Wo + bo -> B2
    mfma_gemm<0><<<dim3(2, NTOK/128), 512, 0, stream>>>(
        B1, B1, 512, 512, WB + WOO, bo + l*DD, nullptr, nullptr,
        B2, nullptr, nullptr);
    // fused gate/upd: gate -> B3 (sigmoid), upd -> B4
    mfma_gemm<2><<<dim3(4, NTOK/128), 512, 0, stream>>>(
        B2, mem, 512, 1024, WB + WGO,
        bg + l*DD, bu + l*DD, nullptr, B3, B4, nullptr);
    // mem update + LN -> h (B1)
    memln_kernel<<<NTOK/4, 256, 0, stream>>>(
        B2, B3, B4, mem, lng + l*DD, lnb + l*DD, B1);
  }

  // Temporal conv as GEMM: A = h [8192, 2048]; conv W^T -> WB; c -> B3
  repack_conv<<<4096, 256, 0, stream>>>(convw, WB);
  mfma_gemm<0><<<dim3(2, 8192/128), 512, 0, stream>>>(
      B1, B1, 2048, 2048, WB, convb, nullptr, nullptr, B3, nullptr, nullptr);

  // LN -> LN -> out projection (fp32 out)
  final_kernel<<<8192/4, 256, 0, stream>>>(
      B3, cng, cnb, ong, onb, Wout, bout, outp);
}

// Round 12
// 1422.421 us; speedup vs baseline: 1.6569x; 1.1127x over previous
//
#include <hip/hip_runtime.h>

// Problem constants
#define BATCH   4
#define SEQ     8192
#define NTOK    32768      // BATCH*SEQ
#define FF      32
#define FDIM    128
#define DD      512
#define HEADS   8
#define HDIM    64
#define WINSZ   256
#define NBLK    32         // SEQ/WINSZ
#define LAYERS  4

typedef unsigned short u16;
typedef __attribute__((ext_vector_type(8))) short bf16x8;
typedef __attribute__((ext_vector_type(4))) float f32x4;

__device__ __forceinline__ float u2f(u16 u) {
  return __uint_as_float(((unsigned int)u) << 16);
}
// round-half-up bf16 (2 VALU ops)
__device__ __forceinline__ u16 f2u(float f) {
  return (u16)((__float_as_uint(f) + 0x8000u) >> 16);
}
__device__ __forceinline__ unsigned int pk2(float a, float b) {
  return ((__float_as_uint(a) + 0x8000u) >> 16) |
         ((__float_as_uint(b) + 0x8000u) & 0xffff0000u);
}
__device__ __forceinline__ void ld8(const u16* __restrict__ p, float* o) {
  ushort4 q0 = *(const ushort4*)p;
  ushort4 q1 = *(const ushort4*)(p + 4);
  o[0]=u2f(q0.x); o[1]=u2f(q0.y); o[2]=u2f(q0.z); o[3]=u2f(q0.w);
  o[4]=u2f(q1.x); o[5]=u2f(q1.y); o[6]=u2f(q1.z); o[7]=u2f(q1.w);
}
__device__ __forceinline__ void st8(u16* __restrict__ p, const float* v) {
  uint4 o;
  o.x = pk2(v[0], v[1]); o.y = pk2(v[2], v[3]);
  o.z = pk2(v[4], v[5]); o.w = pk2(v[6], v[7]);
  *(uint4*)p = o;
}
// async global->LDS, 16B per lane; LDS dest = wave-uniform base + lane*16
__device__ __forceinline__ void gl_lds16(const u16* g, u16* l) {
  __builtin_amdgcn_global_load_lds(
      (const __attribute__((address_space(1))) void*)g,
      (__attribute__((address_space(3))) void*)l, 16, 0, 0);
}

// ---------------------------------------------------------------------------
// Embedding: fe = x@W_feat + b_feat ; cat = [fe, emb_temp[ts]]
// ---------------------------------------------------------------------------
__global__ __launch_bounds__(128) void embed_kernel(
    const float* __restrict__ x, const int* __restrict__ ts,
    const float* __restrict__ W_feat, const float* __restrict__ b_feat,
    const float* __restrict__ emb, u16* __restrict__ cat)
{
  const int t = blockIdx.x;
  const int j = threadIdx.x;   // 0..127
  __shared__ float xs[FF];
  if (j < FF) xs[j] = x[(size_t)t*FF + j];
  __syncthreads();
  float fe = b_feat[j];
  #pragma unroll
  for (int f = 0; f < FF; ++f) fe += xs[f] * W_feat[f*FDIM + j];
  cat[(size_t)t*256 + j] = f2u(fe);
  const int tv = ts[t];
  cat[(size_t)t*256 + 128 + j] = f2u(emb[(size_t)tv*FDIM + j]);
}

// ---------------------------------------------------------------------------
// Weight transpose+convert: src fp32 [K][512] -> dst bf16 [512][K]
// ---------------------------------------------------------------------------
__global__ __launch_bounds__(256) void transpose_w(
    const float* __restrict__ src, u16* __restrict__ dst, int K)
{
  __shared__ u16 t[32][34];
  const int bk = blockIdx.x*32, bn = blockIdx.y*32;
  const int c = threadIdx.x & 31, r8 = threadIdx.x >> 5;
  #pragma unroll
  for (int rr = 0; rr < 32; rr += 8)
    t[rr + r8][c] = f2u(src[(size_t)(bk + rr + r8)*512 + bn + c]);
  __syncthreads();
  #pragma unroll
  for (int rr = 0; rr < 32; rr += 8)
    dst[(size_t)(bn + rr + r8)*K + bk + c] = t[c][rr + r8];
}

// Weight slot offsets (u16 elements) within the per-layer buffer
#define WQO 0
#define WKO 262144
#define WVO 524288
#define WOO 786432
#define WGO 1048576
#define WUO 1572864

__global__ __launch_bounds__(256) void convert_layer(
    const float* __restrict__ Wq, const float* __restrict__ Wk,
    const float* __restrict__ Wv, const float* __restrict__ Wo,
    const float* __restrict__ Wg, const float* __restrict__ Wu,
    u16* __restrict__ out)
{
  __shared__ u16 t[32][34];
  const int z = blockIdx.z;
  const int K = (z < 4) ? 512 : 1024;
  const int bk = blockIdx.x*32;
  if (bk >= K) return;
  const int bn = blockIdx.y*32;
  const float* src = (z==0)?Wq:(z==1)?Wk:(z==2)?Wv:(z==3)?Wo:(z==4)?Wg:Wu;
  u16* dst = out + ((z<4) ? (size_t)z*262144 : (size_t)1048576 + (size_t)(z-4)*524288);
  const int c = threadIdx.x & 31, r8 = threadIdx.x >> 5;
  #pragma unroll
  for (int rr = 0; rr < 32; rr += 8)
    t[rr + r8][c] = f2u(src[(size_t)(bk + rr + r8)*512 + bn + c]);
  __syncthreads();
  #pragma unroll
  for (int rr = 0; rr < 32; rr += 8)
    dst[(size_t)(bn + rr + r8)*K + bk + c] = t[c][rr + r8];
}

// conv_w fp32 [o,ch,j] -> bf16 [o][k=j*512+ch]  (transposed-B GEMM-ready)
__global__ __launch_bounds__(256) void repack_conv(
    const float* __restrict__ cw, u16* __restrict__ dst)
{
  const int t = blockIdx.x*256 + threadIdx.x;     // < 512*2048
  const int o  = t >> 11;
  const int kk = t & 2047;
  const int j  = kk >> 9;
  const int ch = kk & 511;
  dst[t] = f2u(cw[(size_t)o*2048 + ch*4 + j]);
}

// ---------------------------------------------------------------------------
// MFMA GEMM v3: BM=128, BN=256, BK=64 (two packed 32-wide sub-tiles ->
// conflict-free gl_lds16 layout, half the barrier drains), 512 thr = 8 waves.
// XCD-aware swizzle (gridY%8==0). LDS 48 KB x 3 blocks/CU (VGPR-capped).
// MODE 0: C0 = A@B + b0 (rowmajor [M][512])
// MODE 1: qkv fused N=1536: seg0->C0(q), seg1->C1(k) rowmajor; seg2->C2(v^T)
// MODE 2: gate/upd fused N=1024: seg0->sigmoid->C0, seg1->C1 (rowmajor)
// A bf16 dual-source (concat, K1%64==0), Bt bf16 [N][K], fp32 accum.
// ---------------------------------------------------------------------------
template<int MODE>
__global__ __launch_bounds__(512) void mfma_gemm(
    const u16* __restrict__ A1, const u16* __restrict__ A2, int K1, int K,
    const u16* __restrict__ Bt,
    const float* __restrict__ b0, const float* __restrict__ b1,
    const float* __restrict__ b2,
    u16* __restrict__ C0, u16* __restrict__ C1, u16* __restrict__ C2)
{
  __shared__ u16 Al0[128*32];   // 8 KB
  __shared__ u16 Al1[128*32];
  __shared__ u16 Bl0[256*32];   // 16 KB
  __shared__ u16 Bl1[256*32];
  const int tid  = threadIdx.x;
  const int lane = tid & 63;
  const int wave = tid >> 6;          // 0..7
  const int wm = (wave & 1) * 64;
  const int wn = (wave >> 1) * 64;    // 0..192
  // XCD swizzle
  const int bid = blockIdx.x + gridDim.x * blockIdx.y;
  const int xcd = bid & 7;
  const int jj  = bid >> 3;
  const int nx  = jj % gridDim.x;
  const int my  = (jj / gridDim.x) * 8 + xcd;
  const int m0 = my * 128;
  const int n0 = nx * 256;
  const int cl = lane & 15, quad = lane >> 4;
  const int arow = tid >> 2;          // 0..127
  const int ak   = (tid & 3) * 8;
  u16* Ad0 = Al0 + wave*512;          // HW adds lane*16B
  u16* Ad1 = Al1 + wave*512;
  u16* Bd00 = Bl0 + wave*512;
  u16* Bd01 = Bl0 + 4096 + wave*512;
  u16* Bd10 = Bl1 + wave*512;
  u16* Bd11 = Bl1 + 4096 + wave*512;
  const int K2 = K - K1;

  f32x4 acc[4][4];
  #pragma unroll
  for (int i = 0; i < 4; ++i)
    #pragma unroll
    for (int j = 0; j < 4; ++j)
      acc[i][j] = (f32x4){0.f, 0.f, 0.f, 0.f};

  for (int k0 = 0; k0 < K; k0 += 64) {
    const int kc0 = k0 + ak;
    const int kc1 = kc0 + 32;
    const u16* a0 = (kc0 < K1) ? A1 + (size_t)(m0 + arow)*K1 + kc0
                               : A2 + (size_t)(m0 + arow)*K2 + (kc0 - K1);
    const u16* a1 = (kc1 < K1) ? A1 + (size_t)(m0 + arow)*K1 + kc1
                               : A2 + (size_t)(m0 + arow)*K2 + (kc1 - K1);
    gl_lds16(a0, Ad0);
    gl_lds16(a1, Ad1);
    gl_lds16(Bt + (size_t)(n0 + arow)*K + kc0,       Bd00);
    gl_lds16(Bt + (size_t)(n0 + 128 + arow)*K + kc0, Bd01);
    gl_lds16(Bt + (size_t)(n0 + arow)*K + kc1,       Bd10);
    gl_lds16(Bt + (size_t)(n0 + 128 + arow)*K + kc1, Bd11);
    __syncthreads();
    #pragma unroll
    for (int sub = 0; sub < 2; ++sub) {
      const u16* Asrc = sub ? Al1 : Al0;
      const u16* Bsrc = sub ? Bl1 : Bl0;
      bf16x8 af[4], bfr[4];
      #pragma unroll
      for (int i = 0; i < 4; ++i) {
        af[i]  = *(const bf16x8*)(Asrc + (wm + i*16 + cl)*32 + quad*8);
        bfr[i] = *(const bf16x8*)(Bsrc + (wn + i*16 + cl)*32 + quad*8);
      }
      #pragma unroll
      for (int i = 0; i < 4; ++i)
        #pragma unroll
        for (int j = 0; j < 4; ++j)
          acc[i][j] = __builtin_amdgcn_mfma_f32_16x16x32_bf16(
              af[i], bfr[j], acc[i][j], 0, 0, 0);
    }
    __syncthreads();
  }
  const int rq = quad * 4;
  const int colbase = n0 + wn;          // 64-aligned -> seg uniform per wave
  const int seg = colbase >> 9;
  const float* bias = (MODE == 0) ? b0 : (seg == 0 ? b0 : (seg == 1 ? b1 : b2));
  u16* dstR = (seg == 0) ? C0 : C1;     // rowmajor dest (seg<2)
  #pragma unroll
  for (int j = 0; j < 4; ++j) {
    const int lc = (colbase & 511) + j*16 + cl;
    const float bb = bias[lc];
    #pragma unroll
    for (int i = 0; i < 4; ++i) {
      const int rbase = m0 + wm + i*16 + rq;
      float v[4];
      #pragma unroll
      for (int r = 0; r < 4; ++r) {
        float t = acc[i][j][r] + bb;
        if (MODE == 2 && seg == 0) t = 1.0f / (1.0f + __expf(-t));
        v[r] = t;
      }
      if (MODE == 1 && seg == 2) {
        uint2 o2;
        o2.x = pk2(v[0], v[1]); o2.y = pk2(v[2], v[3]);
        *(uint2*)(C2 + (size_t)lc*NTOK + rbase) = o2;
      } else {
        #pragma unroll
        for (int r = 0; r < 4; ++r)
          dstR[(size_t)(rbase + r)*DD + lc] = f2u(v[r]);
      }
    }
  }
}

// ---------------------------------------------------------------------------
// MFMA flash attention v5: 32 queries/wave (halved register footprint for
// occupancy), S^T formulation, no-max softmax, shuffle-based P (no LDS P).
// Grid 2048: block = (b, window n, q-half, head); 4 waves x 32 queries.
// Keys [(n-1)*W,(n+1)*W); n==0 -> only [0,W).
// P B-operand frags via intra-wave __shfl from S^T C-layout (see r8 notes).
// vt input dim-major [512][NTOK] (written transposed by the V-GEMM epilogue).
// DEFAULT launch bounds (r9: forced cap -> scratch spill, 2.3x slower).
// ---------------------------------------------------------------------------
#define EXPSC 0.18033688f   // 0.125 * log2(e)
__global__ __launch_bounds__(256) void attn_kernel(
    const u16* __restrict__ q, const u16* __restrict__ k,
    const u16* __restrict__ vt, u16* __restrict__ ctx)
{
  __shared__ u16 Ks[128*72];
  __shared__ u16 Vl[64*136];
  const int bid  = blockIdx.x;
  const int head = bid & 7;
  const int qh   = (bid >> 3) & 1;
  const int n    = (bid >> 4) & 31;
  const int b    = bid >> 9;
  const int tid  = threadIdx.x;
  const int lane = tid & 63;
  const int wave = tid >> 6;
  const int cl   = lane & 15;
  const int quad = lane >> 4;
  const int qtok0 = b*SEQ + n*WINSZ + qh*128 + wave*32;
  const bool hi2 = (lane >= 32);              // quad>=2 -> use pd[2kh+1]
  const int srcA = cl + ((quad & 1) << 5);    // lane of quad' = 2(quad&1)
  const int srcB = srcA + 16;                 // lane of quad' = 2(quad&1)+1

  // Q fragments (B-operand: n=q rows, k-contiguous)
  bf16x8 qf[2][2];
  #pragma unroll
  for (int jf = 0; jf < 2; ++jf)
    #pragma unroll
    for (int kh = 0; kh < 2; ++kh)
      qf[jf][kh] = *(const bf16x8*)(q + (size_t)(qtok0 + jf*16 + cl)*DD
                                      + head*HDIM + kh*32 + quad*8);

  f32x4 oacc[4][2];   // [jd][jq]
  #pragma unroll
  for (int i = 0; i < 4; ++i)
    #pragma unroll
    for (int j = 0; j < 2; ++j)
      oacc[i][j] = (f32x4){0.f, 0.f, 0.f, 0.f};
  float lrun[2] = {0.f, 0.f};

  const int r0 = (n == 0) ? WINSZ : 0;
  const int base_tok = b*SEQ + (n - 1)*WINSZ;
  const int ksr = tid >> 1;          // K stage: key row 0..127
  const int ksc = (tid & 1) * 32;    // 64 B per thread
  const int vsr = tid >> 2;          // V stage: dim row 0..63
  const int vsc = (tid & 3) * 32;    // 64 B per thread

  for (int c0 = r0; c0 < 2*WINSZ; c0 += 128) {
    // ---- stage K [128 keys][64 d] and V^T [64 d][128 keys], 64 B/thread ----
    {
      const u16* ksrc = k + (size_t)(base_tok + c0 + ksr)*DD + head*HDIM + ksc;
      uint4* kd = (uint4*)(Ks + ksr*72 + ksc);
      kd[0] = ((const uint4*)ksrc)[0];
      kd[1] = ((const uint4*)ksrc)[1];
      kd[2] = ((const uint4*)ksrc)[2];
      kd[3] = ((const uint4*)ksrc)[3];
      const u16* vsrc = vt + (size_t)(head*HDIM + vsr)*NTOK + base_tok + c0 + vsc;
      uint4* vd = (uint4*)(Vl + vsr*136 + vsc);
      vd[0] = ((const uint4*)vsrc)[0];
      vd[1] = ((const uint4*)vsrc)[1];
      vd[2] = ((const uint4*)vsrc)[2];
      vd[3] = ((const uint4*)vsrc)[3];
    }
    __syncthreads();
    #pragma unroll
    for (int half = 0; half < 2; ++half) {
      #pragma unroll
      for (int jf = 0; jf < 2; ++jf) {
        // ---- S^T = K·Q^T : sa[i] = D[key 16i+4quad+r][q 16jf+cl] ----
        f32x4 sa[4];
        #pragma unroll
        for (int i = 0; i < 4; ++i) {
          const u16* kr = Ks + (half*64 + i*16 + cl)*72 + quad*8;
          bf16x8 k0 = *(const bf16x8*)kr;
          bf16x8 k1 = *(const bf16x8*)(kr + 32);
          f32x4 s = (f32x4){0.f, 0.f, 0.f, 0.f};
          s = __builtin_amdgcn_mfma_f32_16x16x32_bf16(k0, qf[jf][0], s, 0, 0, 0);
          s = __builtin_amdgcn_mfma_f32_16x16x32_bf16(k1, qf[jf][1], s, 0, 0, 0);
          sa[i] = s;
        }
        // ---- softmax numerators (no max), pack to bf16 pairs ----
        float rs = 0.f;
        unsigned int pd[4][2];
        #pragma unroll
        for (int i = 0; i < 4; ++i) {
          const float p0 = exp2f(sa[i][0] * EXPSC);
          const float p1 = exp2f(sa[i][1] * EXPSC);
          const float p2 = exp2f(sa[i][2] * EXPSC);
          const float p3 = exp2f(sa[i][3] * EXPSC);
          rs += (p0 + p1) + (p2 + p3);
          pd[i][0] = pk2(p0, p1);
          pd[i][1] = pk2(p2, p3);
        }
        rs += __shfl_xor(rs, 16, 64);
        rs += __shfl_xor(rs, 32, 64);
        lrun[jf] += rs;
        // ---- build P B-frags via shuffles, PV MFMA ----
        #pragma unroll
        for (int kh = 0; kh < 2; ++kh) {
          const int aA0 = __shfl((int)pd[2*kh][0],   srcA, 64);
          const int aB0 = __shfl((int)pd[2*kh+1][0], srcA, 64);
          const int aA1 = __shfl((int)pd[2*kh][1],   srcA, 64);
          const int aB1 = __shfl((int)pd[2*kh+1][1], srcA, 64);
          const int cA0 = __shfl((int)pd[2*kh][0],   srcB, 64);
          const int cB0 = __shfl((int)pd[2*kh+1][0], srcB, 64);
          const int cA1 = __shfl((int)pd[2*kh][1],   srcB, 64);
          const int cB1 = __shfl((int)pd[2*kh+1][1], srcB, 64);
          uint4 pw;
          pw.x = hi2 ? aB0 : aA0;
          pw.y = hi2 ? aB1 : aA1;
          pw.z = hi2 ? cB0 : cA0;
          pw.w = hi2 ? cB1 : cA1;
          bf16x8 pf = *(bf16x8*)&pw;
          #pragma unroll
          for (int jd = 0; jd < 4; ++jd) {
            bf16x8 vf = *(const bf16x8*)(Vl + (jd*16 + cl)*136
                                            + half*64 + kh*32 + quad*8);
            oacc[jd][jf] = __builtin_amdgcn_mfma_f32_16x16x32_bf16(
                vf, pf, oacc[jd][jf], 0, 0, 0);
          }
        }
      }
    }
    __syncthreads();
  }
  // ---- epilogue: per lane q = jq*16+cl, dims jd*16+quad*4+r (8B stores) ----
  #pragma unroll
  for (int jq = 0; jq < 2; ++jq) {
    const float inv = 1.0f / lrun[jq];
    u16* crow = ctx + (size_t)(qtok0 + jq*16 + cl)*DD + head*HDIM + quad*4;
    #pragma unroll
    for (int jd = 0; jd < 4; ++jd) {
      uint2 o2;
      o2.x = pk2(oacc[jd][jq][0]*inv, oacc[jd][jq][1]*inv);
      o2.y = pk2(oacc[jd][jq][2]*inv, oacc[jd][jq][3]*inv);
      *(uint2*)(crow + jd*16) = o2;
    }
  }
}

// ---------------------------------------------------------------------------
// new_mem = g*u + (1-g)*mem ; h = LN(a + new_mem)  (wave per token)
// ---------------------------------------------------------------------------
__global__ __launch_bounds__(256) void memln_kernel(
    const u16* __restrict__ a, const u16* __restrict__ gate, const u16* __restrict__ upd,
    u16* __restrict__ mem, const float* __restrict__ lg, const float* __restrict__ lb,
    u16* __restrict__ h)
{
  const int lane = threadIdx.x & 63;
  const int wave = threadIdx.x >> 6;
  const int t = blockIdx.x*4 + wave;
  const size_t base = (size_t)t*DD + lane*8;
  float av[8], gv[8], uv[8], mv[8];
  ld8(a + base, av); ld8(gate + base, gv); ld8(upd + base, uv); ld8(mem + base, mv);
  float s[8], nm[8], sum = 0.f, sq = 0.f;
  #pragma unroll
  for (int e = 0; e < 8; ++e) {
    nm[e] = gv[e]*uv[e] + (1.0f - gv[e])*mv[e];
    s[e]  = av[e] + nm[e];
    sum  += s[e]; sq += s[e]*s[e];
  }
  st8(mem + base, nm);
  for (int o = 32; o > 0; o >>= 1) {
    sum += __shfl_xor(sum, o, 64);
    sq  += __shfl_xor(sq,  o, 64);
  }
  const float mean = sum * (1.0f/512.0f);
  const float var  = sq  * (1.0f/512.0f) - mean*mean;
  const float r = rsqrtf(var + 1e-5f);
  float y[8];
  #pragma unroll
  for (int e = 0; e < 8; ++e) {
    const int ch = lane*8 + e;
    y[e] = (s[e] - mean)*r*lg[ch] + lb[ch];
  }
  st8(h + base, y);
}

// ---------------------------------------------------------------------------
// final: o = LN(LN(c, cn), on) ; out = o @ W_out + b_out  (fp32 out)
// ---------------------------------------------------------------------------
__global__ __launch_bounds__(256) void final_kernel(
    const u16* __restrict__ c,
    const float* __restrict__ cng, const float* __restrict__ cnb,
    const float* __restrict__ ong, const float* __restrict__ onb,
    const float* __restrict__ Wout, const float* __restrict__ bout,
    float* __restrict__ out)
{
  __shared__ float ybuf[4][512];
  const int lane = threadIdx.x & 63;
  const int wave = threadIdx.x >> 6;
  const int t = blockIdx.x*4 + wave;
  const size_t base = (size_t)t*DD + lane*8;
  float x[8];
  ld8(c + base, x);
  float sum = 0.f, sq = 0.f;
  #pragma unroll
  for (int e = 0; e < 8; ++e) { sum += x[e]; sq += x[e]*x[e]; }
  for (int o = 32; o > 0; o >>= 1) { sum += __shfl_xor(sum, o, 64); sq += __shfl_xor(sq, o, 64); }
  float mean = sum * (1.0f/512.0f);
  float var  = sq  * (1.0f/512.0f) - mean*mean;
  float r = rsqrtf(var + 1e-5f);
  float y[8];
  float sum2 = 0.f, sq2 = 0.f;
  #pragma unroll
  for (int e = 0; e < 8; ++e) {
    const int ch = lane*8 + e;
    y[e] = (x[e] - mean)*r*cng[ch] + cnb[ch];
    sum2 += y[e]; sq2 += y[e]*y[e];
  }
  for (int o = 32; o > 0; o >>= 1) { sum2 += __shfl_xor(sum2, o, 64); sq2 += __shfl_xor(sq2, o, 64); }
  mean = sum2 * (1.0f/512.0f);
  var  = sq2  * (1.0f/512.0f) - mean*mean;
  r = rsqrtf(var + 1e-5f);
  #pragma unroll
  for (int e = 0; e < 8; ++e) {
    const int ch = lane*8 + e;
    ybuf[wave][ch] = (y[e] - mean)*r*ong[ch] + onb[ch];
  }
  __syncthreads();
  if (lane < FF) {
    float acc = bout[lane];
    for (int ch = 0; ch < 512; ++ch)
      acc += ybuf[wave][ch] * Wout[ch*FF + lane];
    out[(size_t)t*FF + lane] = acc;
  }
}

// ---------------------------------------------------------------------------
// Workspace (164 MB):
//   mem @0 (32MB persistent bf16), B1 @32MB, B2 @64MB, B3 @96MB, B4 @128MB,
//   WB @160MB (4MB: per-layer transposed bf16 weights / W_emb^T / conv W^T)
// ---------------------------------------------------------------------------
extern "C" void kernel_launch(void* const* d_in, const int* in_sizes, int n_in,
                              void* d_out, int out_size, void* d_ws, size_t ws_size,
                              hipStream_t stream)
{
  const float* x      = (const float*)d_in[0];
  const int*   tstamp = (const int*)d_in[1];
  const float* W_feat = (const float*)d_in[2];
  const float* b_feat = (const float*)d_in[3];
  const float* emb_t  = (const float*)d_in[4];
  const float* W_emb  = (const float*)d_in[5];
  const float* b_emb  = (const float*)d_in[6];
  const float* Wq = (const float*)d_in[7];   const float* bq = (const float*)d_in[8];
  const float* Wk = (const float*)d_in[9];   const float* bk = (const float*)d_in[10];
  const float* Wv = (const float*)d_in[11];  const float* bv = (const float*)d_in[12];
  const float* Wo = (const float*)d_in[13];  const float* bo = (const float*)d_in[14];
  const float* Wg = (const float*)d_in[15];  const float* bg = (const float*)d_in[16];
  const float* Wu = (const float*)d_in[17];  const float* bu = (const float*)d_in[18];
  const float* lng = (const float*)d_in[19]; const float* lnb = (const float*)d_in[20];
  const float* convw = (const float*)d_in[21]; const float* convb = (const float*)d_in[22];
  const float* cng = (const float*)d_in[23]; const float* cnb = (const float*)d_in[24];
  const float* ong = (const float*)d_in[25]; const float* onb = (const float*)d_in[26];
  const float* Wout = (const float*)d_in[27]; const float* bout = (const float*)d_in[28];
  float* outp = (float*)d_out;

  char* ws = (char*)d_ws;
  const size_t MB = 1024u*1024u;
  u16* mem = (u16*)ws;
  u16* B1  = (u16*)(ws + 32*MB);
  u16* B2  = (u16*)(ws + 64*MB);
  u16* B3  = (u16*)(ws + 96*MB);
  u16* B4  = (u16*)(ws + 128*MB);
  u16* WB  = (u16*)(ws + 160*MB);

  hipMemsetAsync(mem, 0, (size_t)NTOK*DD*sizeof(u16), stream);

  // Embedding: cat -> B2 ; W_emb^T -> WB ; h -> B1
  embed_kernel<<<NTOK, 128, 0, stream>>>(x, tstamp, W_feat, b_feat, emb_t, B2);
  transpose_w<<<dim3(8, 16), 256, 0, stream>>>(W_emb, WB, 256);
  mfma_gemm<0><<<dim3(2, NTOK/128), 512, 0, stream>>>(
      B2, B2, 256, 256, WB, b_emb, nullptr, nullptr, B1, nullptr, nullptr);

  for (int l = 0; l < LAYERS; ++l) {
    convert_layer<<<dim3(32, 16, 6), 256, 0, stream>>>(
        Wq + (size_t)l*DD*DD, Wk + (size_t)l*DD*DD, Wv + (size_t)l*DD*DD,
        Wo + (size_t)l*DD*DD, Wg + (size_t)l*2*DD*DD, Wu + (size_t)l*2*DD*DD, WB);
    // fused qkv: q -> B2, k -> B3, v^T -> B4
    mfma_gemm<1><<<dim3(6, NTOK/128), 512, 0, stream>>>(
        B1, B1, 512, 512, WB + WQO,
        bq + l*DD, bk + l*DD, bv + l*DD, B2, B3, B4);
    // ctx -> B1 (h dead)
    attn_kernel<<<BATCH*NBLK*2*HEADS, 256, 0, stream>>>(B2, B3, B4, B1);
    // a = ctx @ Wo + bo -> B2
    mfma_gemm<0><<<dim3(2, NTOK/128), 512, 0, stream>>>(
        B1, B1, 512, 512, WB + WOO, bo + l*DD, nullptr, nullptr,
        B2, nullptr, nullptr);
    // fused gate/upd: gate -> B3 (sigmoid), upd -> B4
    mfma_gemm<2><<<dim3(4, NTOK/128), 512, 0, stream>>>(
        B2, mem, 512, 1024, WB + WGO,
        bg + l*DD, bu + l*DD, nullptr, B3, B4, nullptr);
    // mem update + LN -> h (B1)
    memln_kernel<<<NTOK/4, 256, 0, stream>>>(
        B2, B3, B4, mem, lng + l*DD, lnb + l*DD, B1);
  }

  // Temporal conv as GEMM: A = h [8192, 2048]; conv W^T -> WB; c -> B3
  repack_conv<<<4096, 256, 0, stream>>>(convw, WB);
  mfma_gemm<0><<<dim3(2, 8192/128), 512, 0, stream>>>(
      B1, B1, 2048, 2048, WB, convb, nullptr, nullptr, B3, nullptr, nullptr);

  // LN -> LN -> out projection (fp32 out)
  final_kernel<<<8192/4, 256, 0, stream>>>(
      B3, cng, cnb, ong, onb, Wout, bout, outp);
}